// Round 4
// baseline (2356.574 us; speedup 1.0000x reference)
//
#include <hip/hip_runtime.h>

// RuleGraphNet: 2x TripleConv(+mlp), N=50000 nodes, E=800000 edges.
// Edge mid-GEMM via bf16 MFMA over 128-edge tiles; W in registers; eattr
// staged bf16 in XOR-swizzled LDS; CSR-sorted edges; block owns 40 dst nodes,
// LDS-atomic accumulate, single aggr write with self-term fused.

#define NN 50000
#define NE 800000
#define EHALF 400000
#define NN2 100000
#define RPB 40          // dst nodes per block (NN % RPB == 0 -> 1250 blocks)
#define TS 128          // edge slots per tile

typedef __attribute__((ext_vector_type(4))) float  f32x4;
typedef __attribute__((ext_vector_type(8))) __bf16 bf16x8;
typedef __attribute__((ext_vector_type(4))) __bf16 bf16x4;

// ---------------- generic fused GEMM: C = act(A@B + bias) ----------------
__global__ __launch_bounds__(256)
void gemm_bias_act(const float* __restrict__ A, const float* __restrict__ B,
                   const float* __restrict__ bias, float* __restrict__ C,
                   int M, int K, int Nc, int relu)
{
    __shared__ float As[32][68];
    __shared__ float Bs[32][68];
    const int t = threadIdx.x;
    const int tx = t & 15, ty = t >> 4;
    const int row0 = blockIdx.x * 64, col0 = blockIdx.y * 64;
    float acc[4][4] = {};
    for (int k0 = 0; k0 < K; k0 += 32) {
        for (int i = t; i < 2048; i += 256) {
            int r = i >> 5, kk = i & 31;
            int gr = row0 + r, gk = k0 + kk;
            As[kk][r] = (gr < M && gk < K) ? A[(size_t)gr * K + gk] : 0.f;
        }
        for (int i = t; i < 2048; i += 256) {
            int kk = i >> 6, c = i & 63;
            int gk = k0 + kk, gc = col0 + c;
            Bs[kk][c] = (gk < K && gc < Nc) ? B[(size_t)gk * Nc + gc] : 0.f;
        }
        __syncthreads();
        #pragma unroll
        for (int kk = 0; kk < 32; kk++) {
            float4 av = *(const float4*)&As[kk][ty * 4];
            float4 bv = *(const float4*)&Bs[kk][tx * 4];
            float a[4] = {av.x, av.y, av.z, av.w};
            float b[4] = {bv.x, bv.y, bv.z, bv.w};
            #pragma unroll
            for (int i = 0; i < 4; i++)
                #pragma unroll
                for (int j = 0; j < 4; j++)
                    acc[i][j] = fmaf(a[i], b[j], acc[i][j]);
        }
        __syncthreads();
    }
    #pragma unroll
    for (int i = 0; i < 4; i++) {
        int gr = row0 + ty * 4 + i;
        if (gr >= M) continue;
        #pragma unroll
        for (int j = 0; j < 4; j++) {
            int gc = col0 + tx * 4 + j;
            if (gc >= Nc) continue;
            float v = acc[i][j] + bias[gc];
            if (relu) v = fmaxf(v, 0.f);
            C[(size_t)gr * Nc + gc] = v;
        }
    }
}

// ---------------- CSR build (edges sorted by dst, per half) ----------------
__global__ void zero_ints(int* __restrict__ p, int n)
{
    int i = blockIdx.x * 256 + threadIdx.x;
    if (i < n) p[i] = 0;
}

__global__ void count_edges(const int* __restrict__ dst, int* __restrict__ cnt)
{
    int e = blockIdx.x * 256 + threadIdx.x;
    if (e < NE) atomicAdd(&cnt[dst[e] + (e >= EHALF ? NN : 0)], 1);
}

__global__ void scan_blocks(const int* __restrict__ cnt, int* __restrict__ off,
                            int* __restrict__ bsum, int n)
{
    __shared__ int s[256];
    int t = threadIdx.x, g = blockIdx.x * 256 + t;
    int v = (g < n) ? cnt[g] : 0;
    s[t] = v; __syncthreads();
    for (int d = 1; d < 256; d <<= 1) {
        int add = (t >= d) ? s[t - d] : 0;
        __syncthreads();
        s[t] += add;
        __syncthreads();
    }
    if (g < n) off[g] = s[t] - v;
    if (t == 255) bsum[blockIdx.x] = s[255];
}

__global__ void scan_bsum(int* __restrict__ bsum, int nb)
{
    __shared__ int s[512];
    int t = threadIdx.x;
    int v = (t < nb) ? bsum[t] : 0;
    s[t] = v; __syncthreads();
    for (int d = 1; d < 512; d <<= 1) {
        int add = (t >= d) ? s[t - d] : 0;
        __syncthreads();
        s[t] += add;
        __syncthreads();
    }
    if (t < nb) bsum[t] = s[t] - v;
}

__global__ void scan_add(int* __restrict__ off, const int* __restrict__ bsum,
                         int* __restrict__ cur, int n)
{
    int g = blockIdx.x * 256 + threadIdx.x;
    if (g < n) { int o = off[g] + bsum[blockIdx.x]; off[g] = o; cur[g] = o; }
}

__global__ void scatter_edges(const int* __restrict__ dst, int* __restrict__ cur,
                              int* __restrict__ perm)
{
    int e = blockIdx.x * 256 + threadIdx.x;
    if (e < NE) {
        int pos = atomicAdd(&cur[dst[e] + (e >= EHALF ? NN : 0)], 1);
        perm[pos] = e;
    }
}

// ---------------- fused edge pass (both halves, 128-slot tiles) -----------
// Block owns RPB dst nodes. Per 128-slot tile:
//   stage eattr bf16 (swizzled LDS) -> 64 MFMA/wave vs register W-frags ->
//   epilogue: gather NT dst/src rows, relu, run-merge, LDS-atomic accumulate.
// Final: aggr = accl + self (single write).
template<int ND, int NTS>
__global__ __launch_bounds__(256)
void edge_fused(const float* __restrict__ eattr,   // [E][100]
                const int* __restrict__ eidx,      // [2][E]
                const int* __restrict__ perm,
                const int* __restrict__ off,       // [NN2]
                const float* __restrict__ Wa,      // [100][ND]
                const float* __restrict__ Wb,      // [100][ND]
                const float* __restrict__ NT,      // [NN][NTS]
                const float* __restrict__ self,    // [NN][ND]
                float* __restrict__ aggr,          // [NN][ND]
                int blkd_a, int blks_a, int blkd_b, int blks_b)
{
    __shared__ __align__(16) __bf16 et[TS * 128];   // 32 KB, XOR-swizzled
    __shared__ float accl[RPB * 112];               // 17.9 KB
    __shared__ int eid[TS], esrc[TS], edst[TS];
    const int t = threadIdx.x;
    const int lane = t & 63, w = t >> 6;
    const int mh = w & 1, nh = w >> 1;
    const int l15 = lane & 15, l4 = lane >> 4;
    const int n0 = blockIdx.x * RPB;
    const int colbase = nh * 64 + l15;

    for (int i = t; i < RPB * 112; i += 256) accl[i] = 0.f;
    // zero k-pad columns (k=100..127) once; valid-k region rewritten per tile
    for (int i = t; i < TS * 7; i += 256) {
        int row = i / 7, q = 25 + (i - (i / 7) * 7);
        bf16x4 z;
        z[0] = (__bf16)0.f; z[1] = (__bf16)0.f; z[2] = (__bf16)0.f; z[3] = (__bf16)0.f;
        *(bf16x4*)(et + row * 128 + ((q * 4) ^ ((row & 7) << 3))) = z;
    }

    for (int phase = 0; phase < 2; ++phase) {
        const float* Wm = phase ? Wb : Wa;
        const int blkd = phase ? blkd_b : blkd_a;
        const int blks = phase ? blks_b : blks_a;

        // B-fragments in registers: col = colbase + nt*16, k = ks*32 + l4*8 + j
        bf16x8 wf[4][4];
        #pragma unroll
        for (int nt = 0; nt < 4; ++nt) {
            int col = colbase + nt * 16;
            #pragma unroll
            for (int ks = 0; ks < 4; ++ks) {
                bf16x8 f;
                #pragma unroll
                for (int j = 0; j < 8; ++j) {
                    int k = ks * 32 + l4 * 8 + j;
                    float v = (k < 100 && col < ND) ? Wm[k * ND + col] : 0.f;
                    f[j] = (__bf16)v;
                }
                wf[nt][ks] = f;
            }
        }

        const int base = phase * NN + n0;
        const int p0 = off[base];
        const int p1 = (base + RPB == NN2) ? NE : off[base + RPB];

        for (int pt = p0; pt < p1; pt += TS) {
            __syncthreads();   // protect et/eid vs previous tile (and init)
            if (t < TS) {
                int p = pt + t;
                int e = (p < p1) ? perm[p] : -1;
                eid[t] = e;
                esrc[t] = (e >= 0) ? eidx[e] : -1;
                edst[t] = (e >= 0) ? eidx[NE + e] : -1;
            }
            __syncthreads();
            // stage 128 edge rows as bf16 into swizzled LDS (k<100)
            for (int i = t; i < TS * 25; i += 256) {
                int row = i / 25, q = i - (i / 25) * 25;
                int e = eid[row];
                float4 v = {0.f, 0.f, 0.f, 0.f};
                if (e >= 0) v = *(const float4*)(eattr + (size_t)e * 100 + q * 4);
                bf16x4 b;
                b[0] = (__bf16)v.x; b[1] = (__bf16)v.y;
                b[2] = (__bf16)v.z; b[3] = (__bf16)v.w;
                *(bf16x4*)(et + row * 128 + ((q * 4) ^ ((row & 7) << 3))) = b;
            }
            __syncthreads();

            // 64 MFMA per wave: 4 m-tiles x 4 n-tiles x 4 k-steps
            f32x4 c[4][4] = {};
            const int aswz = (l15 & 7) << 3;
            #pragma unroll
            for (int ks = 0; ks < 4; ++ks) {
                #pragma unroll
                for (int mt = 0; mt < 4; ++mt) {
                    int row = mh * 64 + mt * 16 + l15;
                    bf16x8 a = *(const bf16x8*)(et + row * 128 +
                                                ((ks * 32 + l4 * 8) ^ aswz));
                    #pragma unroll
                    for (int nt = 0; nt < 4; ++nt)
                        c[mt][nt] = __builtin_amdgcn_mfma_f32_16x16x32_bf16(
                            a, wf[nt][ks], c[mt][nt], 0, 0, 0);
                }
            }

            // epilogue: NT gathers + relu + run-merge + LDS accumulate
            #pragma unroll
            for (int mt = 0; mt < 4; ++mt) {
                const int rbase = mh * 64 + mt * 16 + l4 * 4;
                int d[4]; size_t bd[4], bs[4];
                #pragma unroll
                for (int r = 0; r < 4; ++r) {
                    d[r] = edst[rbase + r];
                    int s = esrc[rbase + r];
                    bd[r] = (size_t)(d[r] < 0 ? 0 : d[r]) * NTS + blkd;
                    bs[r] = (size_t)(s < 0 ? 0 : s) * NTS + blks;
                }
                #pragma unroll
                for (int nt = 0; nt < 4; ++nt) {
                    int col = colbase + nt * 16;
                    if (col < ND) {
                        int rd = -1; float run = 0.f;
                        #pragma unroll
                        for (int r = 0; r < 4; ++r) {
                            if (d[r] >= 0) {
                                float v = c[mt][nt][r] + NT[bd[r] + col] + NT[bs[r] + col];
                                v = fmaxf(v, 0.f);
                                if (d[r] == rd) run += v;
                                else {
                                    if (rd >= 0)
                                        atomicAdd(&accl[(rd - n0) * 112 + col], run);
                                    rd = d[r]; run = v;
                                }
                            }
                        }
                        if (rd >= 0) atomicAdd(&accl[(rd - n0) * 112 + col], run);
                    }
                }
            }
        }
    }
    __syncthreads();
    for (int i = t; i < RPB * ND; i += 256) {
        int n = i / ND, cidx = i - n * ND;
        size_t g = (size_t)(n0 + n) * ND + cidx;
        aggr[g] = accl[n * 112 + cidx] + self[g];
    }
}

// ---------------- weight assembly (padded, 16B-aligned column blocks) -----
__global__ void assemble(const float* __restrict__ l1a, const float* __restrict__ l1ab,
                         const float* __restrict__ l1b, const float* __restrict__ l1bb,
                         const float* __restrict__ l2a, const float* __restrict__ l2ab,
                         const float* __restrict__ l2b, const float* __restrict__ l2bb,
                         float* __restrict__ W1, float* __restrict__ b1,
                         float* __restrict__ W2, float* __restrict__ b2)
{
    int i = blockIdx.x * 256 + threadIdx.x;
    if (i < 107 * 432) {
        int k = i / 432, c = i % 432;
        int q = c / 108, cc = c - q * 108;
        float v = 0.f;
        if (cc < 107) {
            if (q == 0)      v = l1a[k * 107 + cc];
            else if (q == 1) v = l1a[(207 + k) * 107 + cc];
            else if (q == 2) v = l1b[k * 107 + cc];
            else             v = l1b[(207 + k) * 107 + cc];
        }
        W1[i] = v;
    }
    if (i < 432) {
        int q = i / 108, cc = i - q * 108;
        b1[i] = (cc < 107) ? (q == 0 ? l1ab[cc] : (q == 3 ? l1bb[cc] : 0.f)) : 0.f;
    }
    if (i < 100 * 416) {
        int k = i / 416, c = i % 416;
        int q = c / 104, cc = c - q * 104;
        float v = 0.f;
        if (cc < 100) {
            if (q == 0)      v = l2a[k * 100 + cc];
            else if (q == 1) v = l2a[(200 + k) * 100 + cc];
            else if (q == 2) v = l2b[k * 100 + cc];
            else             v = l2b[(200 + k) * 100 + cc];
        }
        W2[i] = v;
    }
    if (i < 416) {
        int q = i / 104, cc = i - q * 104;
        b2[i] = (cc < 100) ? (q == 0 ? l2ab[cc] : (q == 3 ? l2bb[cc] : 0.f)) : 0.f;
    }
}

extern "C" void kernel_launch(void* const* d_in, const int* in_sizes, int n_in,
                              void* d_out, int out_size, void* d_ws, size_t ws_size,
                              hipStream_t stream)
{
    const float* x    = (const float*)d_in[0];
    const int*   eidx = (const int*)d_in[1];
    const float* eatt = (const float*)d_in[2];
    const float* l1aw = (const float*)d_in[3];
    const float* l1ab = (const float*)d_in[4];
    const float* l1bw = (const float*)d_in[5];
    const float* l1bb = (const float*)d_in[6];
    const float* m1w1 = (const float*)d_in[7];
    const float* m1b1 = (const float*)d_in[8];
    const float* m1w2 = (const float*)d_in[9];
    const float* m1b2 = (const float*)d_in[10];
    const float* l2aw = (const float*)d_in[11];
    const float* l2ab = (const float*)d_in[12];
    const float* l2bw = (const float*)d_in[13];
    const float* l2bb = (const float*)d_in[14];
    const float* m2w1 = (const float*)d_in[15];
    const float* m2b1 = (const float*)d_in[16];
    const float* m2w2 = (const float*)d_in[17];
    const float* m2b2 = (const float*)d_in[18];
    float* out = (float*)d_out;

    // workspace layout (4-byte units)
    float* ws   = (float*)d_ws;
    float* NT   = ws;                                   // 50000*432 = 21,600,000
    float* bufA = NT + (size_t)50000 * 432;             // 5,350,000 (aggr1/aggr2)
    float* bufB = bufA + 5350000;                       // 5,000,000 (t1, t2)
    float* bufC = bufB + 5000000;                       // 5,000,000 (h)
    float* W1   = bufC + 5000000;                       // 46,224
    float* b1v  = W1 + 46224;                           // 432
    float* W2   = b1v + 432;                            // 41,600
    float* b2v  = W2 + 41600;                           // 416
    int*   off  = (int*)(b2v + 416);                    // 100,000
    int*   cur  = off + NN2;                            // 100,000
    int*   bsum = cur + NN2;                            // 512
    int*   perm = bsum + 512;                           // 800,000

    const int* dst = eidx + NE;

    assemble<<<181, 256, 0, stream>>>(l1aw, l1ab, l1bw, l1bb, l2aw, l2ab, l2bw, l2bb,
                                      W1, b1v, W2, b2v);

    // ---- CSR build (dst-sorted edge permutation, per half) ----
    zero_ints<<<(NN2 + 255) / 256, 256, 0, stream>>>(cur, NN2);
    count_edges<<<(NE + 255) / 256, 256, 0, stream>>>(dst, cur);
    scan_blocks<<<(NN2 + 255) / 256, 256, 0, stream>>>(cur, off, bsum, NN2);
    scan_bsum<<<1, 512, 0, stream>>>(bsum, (NN2 + 255) / 256);
    scan_add<<<(NN2 + 255) / 256, 256, 0, stream>>>(off, bsum, cur, NN2);
    scatter_edges<<<(NE + 255) / 256, 256, 0, stream>>>(dst, cur, perm);

    const int EG = NN / RPB;   // 1250

    // ---- conv1 ----
    dim3 gNT1((NN + 63) / 64, (432 + 63) / 64);
    gemm_bias_act<<<gNT1, 256, 0, stream>>>(x, W1, b1v, NT, NN, 107, 432, 0);
    edge_fused<107, 432><<<EG, 256, 0, stream>>>(eatt, eidx, perm, off,
                                                 l1aw + 107 * 107, l1bw + 107 * 107,
                                                 NT, x, bufA, 0, 108, 324, 216);
    dim3 gM1((NN + 63) / 64, 2);
    gemm_bias_act<<<gM1, 256, 0, stream>>>(bufA, m1w1, m1b1, bufB, NN, 107, 100, 1);
    gemm_bias_act<<<gM1, 256, 0, stream>>>(bufB, m1w2, m1b2, bufC, NN, 100, 100, 1);

    // ---- conv2 ----  (h in bufC)
    dim3 gNT2((NN + 63) / 64, (416 + 63) / 64);
    gemm_bias_act<<<gNT2, 256, 0, stream>>>(bufC, W2, b2v, NT, NN, 100, 416, 0);
    edge_fused<100, 416><<<EG, 256, 0, stream>>>(eatt, eidx, perm, off,
                                                 l2aw + 100 * 100, l2bw + 100 * 100,
                                                 NT, bufC, bufA, 0, 104, 312, 208);
    dim3 gM2a((NN + 63) / 64, 1);
    gemm_bias_act<<<gM2a, 256, 0, stream>>>(bufA, m2w1, m2b1, bufB, NN, 100, 64, 1);
    dim3 gM2b((NN + 63) / 64, 2);
    gemm_bias_act<<<gM2b, 256, 0, stream>>>(bufB, m2w2, m2b2, out, NN, 64, 100, 0);
}

// Round 5
// 1980.467 us; speedup vs baseline: 1.1899x; 1.1899x over previous
//
#include <hip/hip_runtime.h>

// RuleGraphNet: 2x TripleConv(+mlp), N=50000 nodes, E=800000 edges.
// Edge pass split in two:
//   edge_gemm: dense streaming MFMA GEMM  MT[e] = eattr[e] @ Wmid  (bf16 out)
//   edge_aggr: lean gather/relu/aggregate over CSR-sorted edges, LDS accumulate
// Node-side transforms as dense GEMM; self term fused into aggr write.

#define NN 50000
#define NE 800000
#define EHALF 400000
#define NN2 100000
#define NPB 16          // dst nodes per edge_aggr block (NN % NPB == 0)

typedef __attribute__((ext_vector_type(4))) float  f32x4;
typedef __attribute__((ext_vector_type(8))) __bf16 bf16x8;
typedef __attribute__((ext_vector_type(4))) __bf16 bf16x4;

// ---------------- generic fused GEMM: C = act(A@B + bias) ----------------
__global__ __launch_bounds__(256)
void gemm_bias_act(const float* __restrict__ A, const float* __restrict__ B,
                   const float* __restrict__ bias, float* __restrict__ C,
                   int M, int K, int Nc, int relu)
{
    __shared__ float As[32][68];
    __shared__ float Bs[32][68];
    const int t = threadIdx.x;
    const int tx = t & 15, ty = t >> 4;
    const int row0 = blockIdx.x * 64, col0 = blockIdx.y * 64;
    float acc[4][4] = {};
    for (int k0 = 0; k0 < K; k0 += 32) {
        for (int i = t; i < 2048; i += 256) {
            int r = i >> 5, kk = i & 31;
            int gr = row0 + r, gk = k0 + kk;
            As[kk][r] = (gr < M && gk < K) ? A[(size_t)gr * K + gk] : 0.f;
        }
        for (int i = t; i < 2048; i += 256) {
            int kk = i >> 6, c = i & 63;
            int gk = k0 + kk, gc = col0 + c;
            Bs[kk][c] = (gk < K && gc < Nc) ? B[(size_t)gk * Nc + gc] : 0.f;
        }
        __syncthreads();
        #pragma unroll
        for (int kk = 0; kk < 32; kk++) {
            float4 av = *(const float4*)&As[kk][ty * 4];
            float4 bv = *(const float4*)&Bs[kk][tx * 4];
            float a[4] = {av.x, av.y, av.z, av.w};
            float b[4] = {bv.x, bv.y, bv.z, bv.w};
            #pragma unroll
            for (int i = 0; i < 4; i++)
                #pragma unroll
                for (int j = 0; j < 4; j++)
                    acc[i][j] = fmaf(a[i], b[j], acc[i][j]);
        }
        __syncthreads();
    }
    #pragma unroll
    for (int i = 0; i < 4; i++) {
        int gr = row0 + ty * 4 + i;
        if (gr >= M) continue;
        #pragma unroll
        for (int j = 0; j < 4; j++) {
            int gc = col0 + tx * 4 + j;
            if (gc >= Nc) continue;
            float v = acc[i][j] + bias[gc];
            if (relu) v = fmaxf(v, 0.f);
            C[(size_t)gr * Nc + gc] = v;
        }
    }
}

// ---------------- CSR build (edges sorted by dst, per half) ----------------
__global__ void zero_ints(int* __restrict__ p, int n)
{
    int i = blockIdx.x * 256 + threadIdx.x;
    if (i < n) p[i] = 0;
}

__global__ void count_edges(const int* __restrict__ dst, int* __restrict__ cnt)
{
    int e = blockIdx.x * 256 + threadIdx.x;
    if (e < NE) atomicAdd(&cnt[dst[e] + (e >= EHALF ? NN : 0)], 1);
}

__global__ void scan_blocks(const int* __restrict__ cnt, int* __restrict__ off,
                            int* __restrict__ bsum, int n)
{
    __shared__ int s[256];
    int t = threadIdx.x, g = blockIdx.x * 256 + t;
    int v = (g < n) ? cnt[g] : 0;
    s[t] = v; __syncthreads();
    for (int d = 1; d < 256; d <<= 1) {
        int add = (t >= d) ? s[t - d] : 0;
        __syncthreads();
        s[t] += add;
        __syncthreads();
    }
    if (g < n) off[g] = s[t] - v;
    if (t == 255) bsum[blockIdx.x] = s[255];
}

__global__ void scan_bsum(int* __restrict__ bsum, int nb)
{
    __shared__ int s[512];
    int t = threadIdx.x;
    int v = (t < nb) ? bsum[t] : 0;
    s[t] = v; __syncthreads();
    for (int d = 1; d < 512; d <<= 1) {
        int add = (t >= d) ? s[t - d] : 0;
        __syncthreads();
        s[t] += add;
        __syncthreads();
    }
    if (t < nb) bsum[t] = s[t] - v;
}

__global__ void scan_add(int* __restrict__ off, const int* __restrict__ bsum,
                         int* __restrict__ cur, int n)
{
    int g = blockIdx.x * 256 + threadIdx.x;
    if (g < n) { int o = off[g] + bsum[blockIdx.x]; off[g] = o; cur[g] = o; }
}

__global__ void scatter_edges(const int* __restrict__ dst, int* __restrict__ cur,
                              int* __restrict__ perm)
{
    int e = blockIdx.x * 256 + threadIdx.x;
    if (e < NE) {
        int pos = atomicAdd(&cur[dst[e] + (e >= EHALF ? NN : 0)], 1);
        perm[pos] = e;
    }
}

// ---------------- edge_gemm: MT[e] = eattr[e] @ W  (bf16, stride 112) ------
// One 128-edge tile per block, natural edge order (streaming reads/writes).
template<int ND>
__global__ __launch_bounds__(256)
void edge_gemm(const float* __restrict__ eattr,   // [E][100]
               const float* __restrict__ W,       // [100][ND]
               __bf16* __restrict__ MT,           // [EHALF][112] (per phase)
               int ebase)
{
    __shared__ __align__(16) __bf16 et[128 * 128];   // 32 KB, XOR-swizzled
    const int t = threadIdx.x;
    const int lane = t & 63, w = t >> 6;
    const int mh = w & 1, nh = w >> 1;
    const int l15 = lane & 15, l4 = lane >> 4;
    const size_t tt = blockIdx.x;

    // stage 128 edge rows (k zero-padded to 128) as bf16, swizzled
    for (int i = t; i < 128 * 32; i += 256) {
        int row = i >> 5, q = i & 31;
        float4 v = {0.f, 0.f, 0.f, 0.f};
        if (q < 25) v = *(const float4*)(eattr + ((size_t)ebase + tt * 128 + row) * 100 + q * 4);
        bf16x4 b;
        b[0] = (__bf16)v.x; b[1] = (__bf16)v.y; b[2] = (__bf16)v.z; b[3] = (__bf16)v.w;
        *(bf16x4*)(et + row * 128 + ((q * 4) ^ ((row & 7) << 3))) = b;
    }

    // B-fragments in registers: col = nh*64 + nt*16 + l15, k = ks*32 + l4*8 + j
    bf16x8 wf[4][4];
    const int colbase = nh * 64 + l15;
    #pragma unroll
    for (int nt = 0; nt < 4; ++nt) {
        int col = colbase + nt * 16;
        #pragma unroll
        for (int ks = 0; ks < 4; ++ks) {
            bf16x8 f;
            #pragma unroll
            for (int j = 0; j < 8; ++j) {
                int k = ks * 32 + l4 * 8 + j;
                float v = (k < 100 && col < ND) ? W[k * ND + col] : 0.f;
                f[j] = (__bf16)v;
            }
            wf[nt][ks] = f;
        }
    }
    __syncthreads();

    f32x4 c[4][4] = {};
    const int aswz = (l15 & 7) << 3;
    #pragma unroll
    for (int ks = 0; ks < 4; ++ks) {
        #pragma unroll
        for (int mt = 0; mt < 4; ++mt) {
            int row = mh * 64 + mt * 16 + l15;
            bf16x8 a = *(const bf16x8*)(et + row * 128 + ((ks * 32 + l4 * 8) ^ aswz));
            #pragma unroll
            for (int nt = 0; nt < 4; ++nt)
                c[mt][nt] = __builtin_amdgcn_mfma_f32_16x16x32_bf16(
                    a, wf[nt][ks], c[mt][nt], 0, 0, 0);
        }
    }

    // store bf16 (cols >= 112 dropped; cols ND..111 are zeros)
    #pragma unroll
    for (int mt = 0; mt < 4; ++mt) {
        #pragma unroll
        for (int nt = 0; nt < 4; ++nt) {
            int col = colbase + nt * 16;
            if (col < 112) {
                #pragma unroll
                for (int r = 0; r < 4; ++r) {
                    int row = mh * 64 + mt * 16 + l4 * 4 + r;
                    MT[(tt * 128 + row) * 112 + col] = (__bf16)c[mt][nt][r];
                }
            }
        }
    }
}

// ---------------- edge_aggr: gather + relu + aggregate ----------------
// 128 threads; thread owns column c; block owns NPB dst nodes; walks the
// CSR p-range 4 edges at a time. Thread-exclusive columns -> plain LDS +=.
template<int ND, int NTS>
__global__ __launch_bounds__(128)
void edge_aggr(const __bf16* __restrict__ MT,     // [EHALF][112]
               const int* __restrict__ eidx,      // [2][E]
               const int* __restrict__ perm,
               const int* __restrict__ off,       // [NN2]
               const float* __restrict__ NT,      // [NN][NTS]
               const float* __restrict__ self,    // [NN][ND]
               float* __restrict__ aggr,          // [NN][ND]
               int phase, int blkd, int blks, int mode)
{
    __shared__ float accl[NPB * 112];
    const int t = threadIdx.x;
    const int c = t;
    const int n0 = blockIdx.x * NPB;
    for (int i = t; i < NPB * 112; i += 128) accl[i] = 0.f;
    __syncthreads();

    const int base = phase * NN + n0;
    const int p0 = off[base];
    const int p1 = (base + NPB == NN2) ? NE : off[base + NPB];
    const int ebase = phase * EHALF;

    for (int p = p0; p < p1; p += 4) {
        int e[4], d[4], s[4];
        #pragma unroll
        for (int i = 0; i < 4; ++i) {
            int pp = p + i;
            e[i] = (pp < p1) ? perm[pp] : -1;
        }
        #pragma unroll
        for (int i = 0; i < 4; ++i) {
            s[i] = (e[i] >= 0) ? eidx[e[i]] : 0;
            d[i] = (e[i] >= 0) ? eidx[NE + e[i]] : -1;
        }
        if (c < ND) {
            float v[4];
            #pragma unroll
            for (int i = 0; i < 4; ++i) {
                if (d[i] >= 0) {
                    float mtv = (float)MT[(size_t)(e[i] - ebase) * 112 + c];
                    float nd = NT[(size_t)d[i] * NTS + blkd + c];
                    float ns = NT[(size_t)s[i] * NTS + blks + c];
                    v[i] = fmaxf(mtv + nd + ns, 0.f);
                } else v[i] = 0.f;
            }
            // run-merge (branches are wave-uniform: d[] is lane-invariant)
            int i = 0;
            while (i < 4) {
                if (d[i] < 0) { ++i; continue; }
                int dd = d[i];
                float sv = v[i];
                int j = i + 1;
                while (j < 4 && d[j] == dd) { sv += v[j]; ++j; }
                accl[(dd - n0) * 112 + c] += sv;
                i = j;
            }
        }
    }
    __syncthreads();
    for (int i = t; i < NPB * ND; i += 128) {
        int n = i / ND, cc = i - n * ND;
        size_t g = (size_t)(n0 + n) * ND + cc;
        float val = accl[n * 112 + cc];
        if (mode == 0) aggr[g] = val + self[g];
        else           aggr[g] += val;
    }
}

// ---------------- weight assembly (padded, 16B-aligned column blocks) -----
__global__ void assemble(const float* __restrict__ l1a, const float* __restrict__ l1ab,
                         const float* __restrict__ l1b, const float* __restrict__ l1bb,
                         const float* __restrict__ l2a, const float* __restrict__ l2ab,
                         const float* __restrict__ l2b, const float* __restrict__ l2bb,
                         float* __restrict__ W1, float* __restrict__ b1,
                         float* __restrict__ W2, float* __restrict__ b2)
{
    int i = blockIdx.x * 256 + threadIdx.x;
    if (i < 107 * 432) {
        int k = i / 432, c = i % 432;
        int q = c / 108, cc = c - q * 108;
        float v = 0.f;
        if (cc < 107) {
            if (q == 0)      v = l1a[k * 107 + cc];
            else if (q == 1) v = l1a[(207 + k) * 107 + cc];
            else if (q == 2) v = l1b[k * 107 + cc];
            else             v = l1b[(207 + k) * 107 + cc];
        }
        W1[i] = v;
    }
    if (i < 432) {
        int q = i / 108, cc = i - q * 108;
        b1[i] = (cc < 107) ? (q == 0 ? l1ab[cc] : (q == 3 ? l1bb[cc] : 0.f)) : 0.f;
    }
    if (i < 100 * 416) {
        int k = i / 416, c = i % 416;
        int q = c / 104, cc = c - q * 104;
        float v = 0.f;
        if (cc < 100) {
            if (q == 0)      v = l2a[k * 100 + cc];
            else if (q == 1) v = l2a[(200 + k) * 100 + cc];
            else if (q == 2) v = l2b[k * 100 + cc];
            else             v = l2b[(200 + k) * 100 + cc];
        }
        W2[i] = v;
    }
    if (i < 416) {
        int q = i / 104, cc = i - q * 104;
        b2[i] = (cc < 100) ? (q == 0 ? l2ab[cc] : (q == 3 ? l2bb[cc] : 0.f)) : 0.f;
    }
}

extern "C" void kernel_launch(void* const* d_in, const int* in_sizes, int n_in,
                              void* d_out, int out_size, void* d_ws, size_t ws_size,
                              hipStream_t stream)
{
    const float* x    = (const float*)d_in[0];
    const int*   eidx = (const int*)d_in[1];
    const float* eatt = (const float*)d_in[2];
    const float* l1aw = (const float*)d_in[3];
    const float* l1ab = (const float*)d_in[4];
    const float* l1bw = (const float*)d_in[5];
    const float* l1bb = (const float*)d_in[6];
    const float* m1w1 = (const float*)d_in[7];
    const float* m1b1 = (const float*)d_in[8];
    const float* m1w2 = (const float*)d_in[9];
    const float* m1b2 = (const float*)d_in[10];
    const float* l2aw = (const float*)d_in[11];
    const float* l2ab = (const float*)d_in[12];
    const float* l2bw = (const float*)d_in[13];
    const float* l2bb = (const float*)d_in[14];
    const float* m2w1 = (const float*)d_in[15];
    const float* m2b1 = (const float*)d_in[16];
    const float* m2w2 = (const float*)d_in[17];
    const float* m2b2 = (const float*)d_in[18];
    float* out = (float*)d_out;

    // workspace layout (4-byte units), total ~222 MB
    float* ws   = (float*)d_ws;
    float* NT   = ws;                                   // 21,600,000
    float* bufA = NT + (size_t)50000 * 432;             // 5,350,000 (aggr)
    float* bufC = bufA + 5350000;                       // 5,000,000 (h)
    float* W1   = bufC + 5000000;                       // 46,224
    float* b1v  = W1 + 46224;                           // 432
    float* W2   = b1v + 432;                            // 41,600
    float* b2v  = W2 + 41600;                           // 416
    int*   off  = (int*)(b2v + 416);                    // 100,000
    int*   cur  = off + NN2;                            // 100,000
    int*   bsum = cur + NN2;                            // 512
    int*   perm = bsum + 512;                           // 800,000
    __bf16* MTb = (__bf16*)(perm + NE);                 // 400,000*112 bf16 = 89.6MB
    float* bufB = (float*)MTb;                          // t1/t2 alias (disjoint lifetime)

    const int* dst = eidx + NE;

    assemble<<<181, 256, 0, stream>>>(l1aw, l1ab, l1bw, l1bb, l2aw, l2ab, l2bw, l2bb,
                                      W1, b1v, W2, b2v);

    // ---- CSR build (dst-sorted edge permutation, per half) ----
    zero_ints<<<(NN2 + 255) / 256, 256, 0, stream>>>(cur, NN2);
    count_edges<<<(NE + 255) / 256, 256, 0, stream>>>(dst, cur);
    scan_blocks<<<(NN2 + 255) / 256, 256, 0, stream>>>(cur, off, bsum, NN2);
    scan_bsum<<<1, 512, 0, stream>>>(bsum, (NN2 + 255) / 256);
    scan_add<<<(NN2 + 255) / 256, 256, 0, stream>>>(off, bsum, cur, NN2);
    scatter_edges<<<(NE + 255) / 256, 256, 0, stream>>>(dst, cur, perm);

    const int TG = EHALF / 128;   // 3125 GEMM tiles per phase
    const int AG = NN / NPB;      // 3125 aggr blocks

    // ---- conv1 ----
    dim3 gNT1((NN + 63) / 64, (432 + 63) / 64);
    edge_gemm<107><<<TG, 256, 0, stream>>>(eatt, l1aw + 107 * 107, MTb, 0);
    gemm_bias_act<<<gNT1, 256, 0, stream>>>(x, W1, b1v, NT, NN, 107, 432, 0);
    edge_aggr<107, 432><<<AG, 128, 0, stream>>>(MTb, eidx, perm, off, NT, x, bufA,
                                                0, 0, 108, 0);
    edge_gemm<107><<<TG, 256, 0, stream>>>(eatt, l1bw + 107 * 107, MTb, EHALF);
    edge_aggr<107, 432><<<AG, 128, 0, stream>>>(MTb, eidx, perm, off, NT, x, bufA,
                                                1, 324, 216, 1);
    dim3 gM1((NN + 63) / 64, 2);
    gemm_bias_act<<<gM1, 256, 0, stream>>>(bufA, m1w1, m1b1, bufB, NN, 107, 100, 1);
    gemm_bias_act<<<gM1, 256, 0, stream>>>(bufB, m1w2, m1b2, bufC, NN, 100, 100, 1);

    // ---- conv2 ----  (h in bufC)
    dim3 gNT2((NN + 63) / 64, (416 + 63) / 64);
    edge_gemm<100><<<TG, 256, 0, stream>>>(eatt, l2aw + 100 * 100, MTb, 0);
    gemm_bias_act<<<gNT2, 256, 0, stream>>>(bufC, W2, b2v, NT, NN, 100, 416, 0);
    edge_aggr<100, 416><<<AG, 128, 0, stream>>>(MTb, eidx, perm, off, NT, bufC, bufA,
                                                0, 0, 104, 0);
    edge_gemm<100><<<TG, 256, 0, stream>>>(eatt, l2bw + 100 * 100, MTb, EHALF);
    edge_aggr<100, 416><<<AG, 128, 0, stream>>>(MTb, eidx, perm, off, NT, bufC, bufA,
                                                1, 312, 208, 1);
    dim3 gM2a((NN + 63) / 64, 1);
    gemm_bias_act<<<gM2a, 256, 0, stream>>>(bufA, m2w1, m2b1, bufB, NN, 100, 64, 1);
    dim3 gM2b((NN + 63) / 64, 2);
    gemm_bias_act<<<gM2b, 256, 0, stream>>>(bufB, m2w2, m2b2, out, NN, 64, 100, 0);
}

// Round 6
// 1877.566 us; speedup vs baseline: 1.2551x; 1.0548x over previous
//
#include <hip/hip_runtime.h>

// RuleGraphNet: 2x TripleConv(+mlp), N=50000 nodes, E=800000 edges.
// ALL matmuls via one bf16-MFMA template (mm_bf16): node transforms, edge
// mid-GEMM (MT, bf16 out), and the two MLPs. Aggregation: CSR-sorted edges,
// LDS index staging + column-owner threads, plain LDS accumulate.

#define NN 50000
#define NE 800000
#define EHALF 400000
#define NN2 100000
#define NPB 16          // dst nodes per edge_aggr block
#define CHUNK 512       // edge index slots staged in LDS per aggr block

typedef __attribute__((ext_vector_type(4))) float  f32x4;
typedef __attribute__((ext_vector_type(8))) __bf16 bf16x8;
typedef __attribute__((ext_vector_type(4))) __bf16 bf16x4;

// ---------------- generic bf16 MFMA GEMM ----------------
// Out[M][ldo] = act(A[M][K] @ W[K][N] + bias), A/W fp32 in, bf16 compute.
// Block: 128 rows x 64 cols (col chunk = blockIdx.y), loops RT row-tiles so
// the register-resident W fragments amortize. 4 waves: mh=rows half, nh=cols half.
template<int K, bool OBF16>
__global__ __launch_bounds__(256)
void mm_bf16(const float* __restrict__ A, const float* __restrict__ W,
             const float* __restrict__ bias, void* __restrict__ Outp,
             int M, int N, int ldo, int RT, int relu)
{
    __shared__ __align__(16) __bf16 et[128 * 128];   // 32 KB A-tile, swizzled
    const int t = threadIdx.x;
    const int lane = t & 63, w = t >> 6;
    const int mh = w & 1, nh = w >> 1;
    const int l15 = lane & 15, l4 = lane >> 4;
    const int cb = blockIdx.y * 64;

    // B-fragments in registers (once per block): col = cb + nh*32 + nt*16 + l15
    bf16x8 wf[2][4];
    const int colbase = cb + nh * 32 + l15;
    #pragma unroll
    for (int nt = 0; nt < 2; ++nt) {
        int col = colbase + nt * 16;
        #pragma unroll
        for (int ks = 0; ks < 4; ++ks) {
            bf16x8 f;
            #pragma unroll
            for (int j = 0; j < 8; ++j) {
                int k = ks * 32 + l4 * 8 + j;
                float v = (k < K && col < N) ? W[k * N + col] : 0.f;
                f[j] = (__bf16)v;
            }
            wf[nt][ks] = f;
        }
    }
    float bv[2] = {0.f, 0.f};
    if (bias) {
        #pragma unroll
        for (int nt = 0; nt < 2; ++nt) {
            int col = colbase + nt * 16;
            if (col < N) bv[nt] = bias[col];
        }
    }

    for (int it = 0; it < RT; ++it) {
        const int row0 = (blockIdx.x * RT + it) * 128;
        if (row0 >= M) break;
        __syncthreads();   // et reuse vs previous tile's reads
        if constexpr (K % 4 == 0) {
            constexpr int QK = K / 4;
            for (int i = t; i < 128 * QK; i += 256) {
                int row = i / QK, q = i - row * QK;
                int gr = row0 + row;
                float4 v = {0.f, 0.f, 0.f, 0.f};
                if (gr < M) v = *(const float4*)(A + (size_t)gr * K + q * 4);
                bf16x4 b;
                b[0] = (__bf16)v.x; b[1] = (__bf16)v.y;
                b[2] = (__bf16)v.z; b[3] = (__bf16)v.w;
                *(bf16x4*)(et + row * 128 + ((q * 4) ^ ((row & 7) << 3))) = b;
            }
            constexpr int QP = (128 - K) / 4;
            for (int i = t; i < 128 * QP; i += 256) {
                int row = i / QP, q = QK + (i - (i / QP) * QP);
                bf16x4 z;
                z[0] = (__bf16)0.f; z[1] = (__bf16)0.f;
                z[2] = (__bf16)0.f; z[3] = (__bf16)0.f;
                *(bf16x4*)(et + row * 128 + ((q * 4) ^ ((row & 7) << 3))) = z;
            }
        } else {
            for (int i = t; i < 128 * 128; i += 256) {
                int row = i >> 7, k = i & 127;
                int gr = row0 + row;
                float v = (k < K && gr < M) ? A[(size_t)gr * K + k] : 0.f;
                et[row * 128 + (k ^ ((row & 7) << 3))] = (__bf16)v;
            }
        }
        __syncthreads();

        f32x4 c[4][2] = {};
        #pragma unroll
        for (int ks = 0; ks < 4; ++ks) {
            #pragma unroll
            for (int mt = 0; mt < 4; ++mt) {
                int arow = mh * 64 + mt * 16 + l15;
                bf16x8 a = *(const bf16x8*)(et + arow * 128 +
                                            ((ks * 32 + l4 * 8) ^ ((l15 & 7) << 3)));
                c[mt][0] = __builtin_amdgcn_mfma_f32_16x16x32_bf16(a, wf[0][ks], c[mt][0], 0, 0, 0);
                c[mt][1] = __builtin_amdgcn_mfma_f32_16x16x32_bf16(a, wf[1][ks], c[mt][1], 0, 0, 0);
            }
        }

        #pragma unroll
        for (int mt = 0; mt < 4; ++mt) {
            #pragma unroll
            for (int nt = 0; nt < 2; ++nt) {
                int col = colbase + nt * 16;
                #pragma unroll
                for (int r = 0; r < 4; ++r) {
                    int row = row0 + mh * 64 + mt * 16 + l4 * 4 + r;
                    if constexpr (OBF16) {
                        if (row < M && col < ldo)
                            ((__bf16*)Outp)[(size_t)row * ldo + col] = (__bf16)c[mt][nt][r];
                    } else {
                        if (row < M && col < N) {
                            float v = c[mt][nt][r] + bv[nt];
                            if (relu) v = fmaxf(v, 0.f);
                            ((float*)Outp)[(size_t)row * ldo + col] = v;
                        }
                    }
                }
            }
        }
    }
}

// ---------------- CSR build (edges sorted by dst, per half) ----------------
__global__ void zero_ints(int* __restrict__ p, int n)
{
    int i = blockIdx.x * 256 + threadIdx.x;
    if (i < n) p[i] = 0;
}

__global__ void count_edges(const int* __restrict__ dst, int* __restrict__ cnt)
{
    int e = blockIdx.x * 256 + threadIdx.x;
    if (e < NE) atomicAdd(&cnt[dst[e] + (e >= EHALF ? NN : 0)], 1);
}

__global__ void scan_blocks(const int* __restrict__ cnt, int* __restrict__ off,
                            int* __restrict__ bsum, int n)
{
    __shared__ int s[256];
    int t = threadIdx.x, g = blockIdx.x * 256 + t;
    int v = (g < n) ? cnt[g] : 0;
    s[t] = v; __syncthreads();
    for (int d = 1; d < 256; d <<= 1) {
        int add = (t >= d) ? s[t - d] : 0;
        __syncthreads();
        s[t] += add;
        __syncthreads();
    }
    if (g < n) off[g] = s[t] - v;
    if (t == 255) bsum[blockIdx.x] = s[255];
}

__global__ void scan_bsum(int* __restrict__ bsum, int nb)
{
    __shared__ int s[512];
    int t = threadIdx.x;
    int v = (t < nb) ? bsum[t] : 0;
    s[t] = v; __syncthreads();
    for (int d = 1; d < 512; d <<= 1) {
        int add = (t >= d) ? s[t - d] : 0;
        __syncthreads();
        s[t] += add;
        __syncthreads();
    }
    if (t < nb) bsum[t] = s[t] - v;
}

__global__ void scan_add(int* __restrict__ off, const int* __restrict__ bsum,
                         int* __restrict__ cur, int n)
{
    int g = blockIdx.x * 256 + threadIdx.x;
    if (g < n) { int o = off[g] + bsum[blockIdx.x]; off[g] = o; cur[g] = o; }
}

__global__ void scatter_edges(const int* __restrict__ dst, int* __restrict__ cur,
                              int* __restrict__ perm)
{
    int e = blockIdx.x * 256 + threadIdx.x;
    if (e < NE) {
        int pos = atomicAdd(&cur[dst[e] + (e >= EHALF ? NN : 0)], 1);
        perm[pos] = e;
    }
}

// ---------------- edge_aggr: gather + relu + aggregate ----------------
// 128 threads; thread owns column c; block owns NPB dst nodes. Indices for a
// CHUNK of CSR slots are bulk-staged into LDS first, then the gather loop
// issues MT/NT row reads with no index dependency. Thread-exclusive columns.
template<int ND, int NTS>
__global__ __launch_bounds__(128)
void edge_aggr(const __bf16* __restrict__ MT,     // [EHALF][112] current phase
               const int* __restrict__ eidx,      // [2][E]
               const int* __restrict__ perm,
               const int* __restrict__ off,       // [NN2]
               const float* __restrict__ NT,      // [NN][NTS]
               const float* __restrict__ self,    // [NN][ND]
               float* __restrict__ aggr,          // [NN][ND]
               int phase, int blkd, int blks, int mode)
{
    __shared__ float accl[NPB * 112];
    __shared__ int lee[CHUNK], les[CHUNK], led[CHUNK];
    const int t = threadIdx.x;
    const int c = t;
    const int n0 = blockIdx.x * NPB;
    for (int i = t; i < NPB * 112; i += 128) accl[i] = 0.f;

    const int base = phase * NN + n0;
    const int p0 = off[base];
    const int p1 = (base + NPB == NN2) ? NE : off[base + NPB];
    const int ebase = phase * EHALF;

    for (int pc = p0; pc < p1; pc += CHUNK) {
        const int cnt = min(CHUNK, p1 - pc);
        __syncthreads();   // accl init / previous chunk fully consumed
        for (int i = t; i < cnt; i += 128) {
            int e = perm[pc + i];
            lee[i] = e - ebase;
            les[i] = eidx[e];
            led[i] = eidx[NE + e];
        }
        __syncthreads();
        for (int g = 0; g < cnt; g += 4) {
            int ee[4], dd[4], ss[4];
            #pragma unroll
            for (int i = 0; i < 4; ++i) {
                int gi = g + i;
                bool ok = gi < cnt;
                ee[i] = ok ? lee[gi] : 0;
                dd[i] = ok ? led[gi] : -1;
                ss[i] = ok ? les[gi] : 0;
            }
            if (c < ND) {
                float v[4];
                #pragma unroll
                for (int i = 0; i < 4; ++i) {
                    v[i] = 0.f;
                    if (dd[i] >= 0) {
                        float mtv = (float)MT[(size_t)ee[i] * 112 + c];
                        float nd = NT[(size_t)dd[i] * NTS + blkd + c];
                        float ns = NT[(size_t)ss[i] * NTS + blks + c];
                        v[i] = fmaxf(mtv + nd + ns, 0.f);
                    }
                }
                int i = 0;
                while (i < 4) {
                    if (dd[i] < 0) { ++i; continue; }
                    int d2 = dd[i]; float sv = v[i]; int j = i + 1;
                    while (j < 4 && dd[j] == d2) { sv += v[j]; ++j; }
                    accl[(d2 - n0) * 112 + c] += sv;
                    i = j;
                }
            }
        }
    }
    __syncthreads();
    for (int i = t; i < NPB * ND; i += 128) {
        int n = i / ND, cc = i - n * ND;
        size_t g = (size_t)(n0 + n) * ND + cc;
        float val = accl[n * 112 + cc];
        aggr[g] = (mode == 0) ? (val + self[g]) : (aggr[g] + val);
    }
}

// ---------------- weight assembly (padded, 16B-aligned column blocks) -----
__global__ void assemble(const float* __restrict__ l1a, const float* __restrict__ l1ab,
                         const float* __restrict__ l1b, const float* __restrict__ l1bb,
                         const float* __restrict__ l2a, const float* __restrict__ l2ab,
                         const float* __restrict__ l2b, const float* __restrict__ l2bb,
                         float* __restrict__ W1, float* __restrict__ b1,
                         float* __restrict__ W2, float* __restrict__ b2)
{
    int i = blockIdx.x * 256 + threadIdx.x;
    if (i < 107 * 432) {
        int k = i / 432, c = i % 432;
        int q = c / 108, cc = c - q * 108;
        float v = 0.f;
        if (cc < 107) {
            if (q == 0)      v = l1a[k * 107 + cc];
            else if (q == 1) v = l1a[(207 + k) * 107 + cc];
            else if (q == 2) v = l1b[k * 107 + cc];
            else             v = l1b[(207 + k) * 107 + cc];
        }
        W1[i] = v;
    }
    if (i < 432) {
        int q = i / 108, cc = i - q * 108;
        b1[i] = (cc < 107) ? (q == 0 ? l1ab[cc] : (q == 3 ? l1bb[cc] : 0.f)) : 0.f;
    }
    if (i < 100 * 416) {
        int k = i / 416, c = i % 416;
        int q = c / 104, cc = c - q * 104;
        float v = 0.f;
        if (cc < 100) {
            if (q == 0)      v = l2a[k * 100 + cc];
            else if (q == 1) v = l2a[(200 + k) * 100 + cc];
            else if (q == 2) v = l2b[k * 100 + cc];
            else             v = l2b[(200 + k) * 100 + cc];
        }
        W2[i] = v;
    }
    if (i < 416) {
        int q = i / 104, cc = i - q * 104;
        b2[i] = (cc < 100) ? (q == 0 ? l2ab[cc] : (q == 3 ? l2bb[cc] : 0.f)) : 0.f;
    }
}

extern "C" void kernel_launch(void* const* d_in, const int* in_sizes, int n_in,
                              void* d_out, int out_size, void* d_ws, size_t ws_size,
                              hipStream_t stream)
{
    const float* x    = (const float*)d_in[0];
    const int*   eidx = (const int*)d_in[1];
    const float* eatt = (const float*)d_in[2];
    const float* l1aw = (const float*)d_in[3];
    const float* l1ab = (const float*)d_in[4];
    const float* l1bw = (const float*)d_in[5];
    const float* l1bb = (const float*)d_in[6];
    const float* m1w1 = (const float*)d_in[7];
    const float* m1b1 = (const float*)d_in[8];
    const float* m1w2 = (const float*)d_in[9];
    const float* m1b2 = (const float*)d_in[10];
    const float* l2aw = (const float*)d_in[11];
    const float* l2ab = (const float*)d_in[12];
    const float* l2bw = (const float*)d_in[13];
    const float* l2bb = (const float*)d_in[14];
    const float* m2w1 = (const float*)d_in[15];
    const float* m2b1 = (const float*)d_in[16];
    const float* m2w2 = (const float*)d_in[17];
    const float* m2b2 = (const float*)d_in[18];
    float* out = (float*)d_out;

    // workspace layout (4-byte units), ~222 MB total (same as proven)
    float* ws   = (float*)d_ws;
    float* NT   = ws;                                   // 21,600,000
    float* bufA = NT + (size_t)50000 * 432;             // 5,350,000 (aggr)
    float* bufC = bufA + 5350000;                       // 5,000,000 (h)
    float* W1   = bufC + 5000000;                       // 46,224
    float* b1v  = W1 + 46224;                           // 432
    float* W2   = b1v + 432;                            // 41,600
    float* b2v  = W2 + 41600;                           // 416
    int*   off  = (int*)(b2v + 416);                    // 100,000
    int*   cur  = off + NN2;                            // 100,000
    int*   bsum = cur + NN2;                            // 512
    int*   perm = bsum + 512;                           // 800,000
    __bf16* MTb = (__bf16*)(perm + NE);                 // 400,000*112 bf16 = 89.6 MB
    float* bufB = (float*)MTb;                          // t1/t2 alias (disjoint lifetime)

    const int* dst = eidx + NE;

    assemble<<<181, 256, 0, stream>>>(l1aw, l1ab, l1bw, l1bb, l2aw, l2ab, l2bw, l2bb,
                                      W1, b1v, W2, b2v);

    // ---- CSR build (dst-sorted edge permutation, per half) ----
    zero_ints<<<(NN2 + 255) / 256, 256, 0, stream>>>(cur, NN2);
    count_edges<<<(NE + 255) / 256, 256, 0, stream>>>(dst, cur);
    scan_blocks<<<(NN2 + 255) / 256, 256, 0, stream>>>(cur, off, bsum, NN2);
    scan_bsum<<<1, 512, 0, stream>>>(bsum, (NN2 + 255) / 256);
    scan_add<<<(NN2 + 255) / 256, 256, 0, stream>>>(off, bsum, cur, NN2);
    scatter_edges<<<(NE + 255) / 256, 256, 0, stream>>>(dst, cur, perm);

    const int AG = NN / NPB;   // 3125 aggr blocks

    // ---- conv1 ----
    // NT1 = x @ W1cat + b1cat   [50000][432]
    mm_bf16<107, false><<<dim3(98, 7), 256, 0, stream>>>(x, W1, b1v, NT,
                                                         NN, 432, 432, 4, 0);
    // MT(a) = eattr[0:E/2] @ W1a_mid  (bf16)
    mm_bf16<100, true><<<dim3(625, 2), 256, 0, stream>>>(eatt, l1aw + 107 * 107,
                                                         nullptr, MTb, EHALF, 107, 112, 5, 0);
    edge_aggr<107, 432><<<AG, 128, 0, stream>>>(MTb, eidx, perm, off, NT, x, bufA,
                                                0, 0, 108, 0);
    mm_bf16<100, true><<<dim3(625, 2), 256, 0, stream>>>(eatt + (size_t)EHALF * 100,
                                                         l1bw + 107 * 107,
                                                         nullptr, MTb, EHALF, 107, 112, 5, 0);
    edge_aggr<107, 432><<<AG, 128, 0, stream>>>(MTb, eidx, perm, off, NT, x, bufA,
                                                1, 324, 216, 1);
    // mlp1: t1 = relu(aggr@w1+b1); h = relu(t1@w2+b2)
    mm_bf16<107, false><<<dim3(98, 2), 256, 0, stream>>>(bufA, m1w1, m1b1, bufB,
                                                         NN, 100, 100, 4, 1);
    mm_bf16<100, false><<<dim3(98, 2), 256, 0, stream>>>(bufB, m1w2, m1b2, bufC,
                                                         NN, 100, 100, 4, 1);

    // ---- conv2 ----  (h in bufC)
    mm_bf16<100, false><<<dim3(98, 7), 256, 0, stream>>>(bufC, W2, b2v, NT,
                                                         NN, 416, 416, 4, 0);
    mm_bf16<100, true><<<dim3(625, 2), 256, 0, stream>>>(eatt, l2aw + 100 * 100,
                                                         nullptr, MTb, EHALF, 100, 112, 5, 0);
    edge_aggr<100, 416><<<AG, 128, 0, stream>>>(MTb, eidx, perm, off, NT, bufC, bufA,
                                                0, 0, 104, 0);
    mm_bf16<100, true><<<dim3(625, 2), 256, 0, stream>>>(eatt + (size_t)EHALF * 100,
                                                         l2bw + 100 * 100,
                                                         nullptr, MTb, EHALF, 100, 112, 5, 0);
    edge_aggr<100, 416><<<AG, 128, 0, stream>>>(MTb, eidx, perm, off, NT, bufC, bufA,
                                                1, 312, 208, 1);
    // mlp2: t2 = relu(aggr@w1+b1); out = t2@w2+b2
    mm_bf16<100, false><<<dim3(98, 1), 256, 0, stream>>>(bufA, m2w1, m2b1, bufB,
                                                         NN, 64, 64, 4, 1);
    mm_bf16<64, false><<<dim3(98, 2), 256, 0, stream>>>(bufB, m2w2, m2b2, out,
                                                        NN, 100, 100, 4, 0);
}

// Round 7
// 1847.097 us; speedup vs baseline: 1.2758x; 1.0165x over previous
//
#include <hip/hip_runtime.h>

// RuleGraphNet: 2x TripleConv(+mlp), N=50000 nodes, E=800000 edges.
// All matmuls via one bf16-MFMA template (mm_bf16). Edge mid-GEMM (MT) is
// written in CSR-permuted order (scatter-store via einv), so the aggregation
// kernel reads MT/src/dst fully sequentially; NT[dst] hoisted per run.

#define NN 50000
#define NE 800000
#define EHALF 400000
#define NN2 100000
#define NPB 8           // dst nodes per edge_aggr block
#define CHUNK 256       // edge slots staged per aggr iteration
#define GB 8            // edges per inner group

typedef __attribute__((ext_vector_type(4))) float  f32x4;
typedef __attribute__((ext_vector_type(8))) __bf16 bf16x8;
typedef __attribute__((ext_vector_type(4))) __bf16 bf16x4;

// ---------------- generic bf16 MFMA GEMM ----------------
// Out[M][ldo] = act(A[M][K] @ W[K][N] + bias); A/W fp32 in, bf16 compute.
// Block: 128 rows x 64 cols (col chunk = blockIdx.y), RT row-tiles per block.
// If rowmap != nullptr (OBF16 path), output row = rowmap[row] - rmbase.
template<int K, bool OBF16>
__global__ __launch_bounds__(256)
void mm_bf16(const float* __restrict__ A, const float* __restrict__ W,
             const float* __restrict__ bias, void* __restrict__ Outp,
             const int* __restrict__ rowmap, int rmbase,
             int M, int N, int ldo, int RT, int relu)
{
    __shared__ __align__(16) __bf16 et[128 * 128];   // 32 KB A-tile, swizzled
    const int t = threadIdx.x;
    const int lane = t & 63, w = t >> 6;
    const int mh = w & 1, nh = w >> 1;
    const int l15 = lane & 15, l4 = lane >> 4;
    const int cb = blockIdx.y * 64;

    // B-fragments in registers (once per block)
    bf16x8 wf[2][4];
    const int colbase = cb + nh * 32 + l15;
    #pragma unroll
    for (int nt = 0; nt < 2; ++nt) {
        int col = colbase + nt * 16;
        #pragma unroll
        for (int ks = 0; ks < 4; ++ks) {
            bf16x8 f;
            #pragma unroll
            for (int j = 0; j < 8; ++j) {
                int k = ks * 32 + l4 * 8 + j;
                float v = (k < K && col < N) ? W[k * N + col] : 0.f;
                f[j] = (__bf16)v;
            }
            wf[nt][ks] = f;
        }
    }
    float bv[2] = {0.f, 0.f};
    if (bias) {
        #pragma unroll
        for (int nt = 0; nt < 2; ++nt) {
            int col = colbase + nt * 16;
            if (col < N) bv[nt] = bias[col];
        }
    }

    for (int it = 0; it < RT; ++it) {
        const int row0 = (blockIdx.x * RT + it) * 128;
        if (row0 >= M) break;
        __syncthreads();   // et reuse vs previous tile's reads
        if constexpr (K % 4 == 0) {
            constexpr int QK = K / 4;
            for (int i = t; i < 128 * QK; i += 256) {
                int row = i / QK, q = i - row * QK;
                int gr = row0 + row;
                float4 v = {0.f, 0.f, 0.f, 0.f};
                if (gr < M) v = *(const float4*)(A + (size_t)gr * K + q * 4);
                bf16x4 b;
                b[0] = (__bf16)v.x; b[1] = (__bf16)v.y;
                b[2] = (__bf16)v.z; b[3] = (__bf16)v.w;
                *(bf16x4*)(et + row * 128 + ((q * 4) ^ ((row & 7) << 3))) = b;
            }
            constexpr int QP = (128 - K) / 4;
            for (int i = t; i < 128 * QP; i += 256) {
                int row = i / QP, q = QK + (i - (i / QP) * QP);
                bf16x4 z;
                z[0] = (__bf16)0.f; z[1] = (__bf16)0.f;
                z[2] = (__bf16)0.f; z[3] = (__bf16)0.f;
                *(bf16x4*)(et + row * 128 + ((q * 4) ^ ((row & 7) << 3))) = z;
            }
        } else {
            for (int i = t; i < 128 * 128; i += 256) {
                int row = i >> 7, k = i & 127;
                int gr = row0 + row;
                float v = (k < K && gr < M) ? A[(size_t)gr * K + k] : 0.f;
                et[row * 128 + (k ^ ((row & 7) << 3))] = (__bf16)v;
            }
        }
        __syncthreads();

        f32x4 c[4][2] = {};
        #pragma unroll
        for (int ks = 0; ks < 4; ++ks) {
            #pragma unroll
            for (int mt = 0; mt < 4; ++mt) {
                int arow = mh * 64 + mt * 16 + l15;
                bf16x8 a = *(const bf16x8*)(et + arow * 128 +
                                            ((ks * 32 + l4 * 8) ^ ((l15 & 7) << 3)));
                c[mt][0] = __builtin_amdgcn_mfma_f32_16x16x32_bf16(a, wf[0][ks], c[mt][0], 0, 0, 0);
                c[mt][1] = __builtin_amdgcn_mfma_f32_16x16x32_bf16(a, wf[1][ks], c[mt][1], 0, 0, 0);
            }
        }

        #pragma unroll
        for (int mt = 0; mt < 4; ++mt) {
            #pragma unroll
            for (int nt = 0; nt < 2; ++nt) {
                int col = colbase + nt * 16;
                #pragma unroll
                for (int r = 0; r < 4; ++r) {
                    int row = row0 + mh * 64 + mt * 16 + l4 * 4 + r;
                    if constexpr (OBF16) {
                        if (row < M && col < ldo) {
                            int ro = rowmap ? (rowmap[row] - rmbase) : row;
                            ((__bf16*)Outp)[(size_t)ro * ldo + col] = (__bf16)c[mt][nt][r];
                        }
                    } else {
                        if (row < M && col < N) {
                            float v = c[mt][nt][r] + bv[nt];
                            if (relu) v = fmaxf(v, 0.f);
                            ((float*)Outp)[(size_t)row * ldo + col] = v;
                        }
                    }
                }
            }
        }
    }
}

// ---------------- CSR build (edges sorted by dst, per half) ----------------
__global__ void zero_ints(int* __restrict__ p, int n)
{
    int i = blockIdx.x * 256 + threadIdx.x;
    if (i < n) p[i] = 0;
}

__global__ void count_edges(const int* __restrict__ dst, int* __restrict__ cnt)
{
    int e = blockIdx.x * 256 + threadIdx.x;
    if (e < NE) atomicAdd(&cnt[dst[e] + (e >= EHALF ? NN : 0)], 1);
}

__global__ void scan_blocks(const int* __restrict__ cnt, int* __restrict__ off,
                            int* __restrict__ bsum, int n)
{
    __shared__ int s[256];
    int t = threadIdx.x, g = blockIdx.x * 256 + t;
    int v = (g < n) ? cnt[g] : 0;
    s[t] = v; __syncthreads();
    for (int d = 1; d < 256; d <<= 1) {
        int add = (t >= d) ? s[t - d] : 0;
        __syncthreads();
        s[t] += add;
        __syncthreads();
    }
    if (g < n) off[g] = s[t] - v;
    if (t == 255) bsum[blockIdx.x] = s[255];
}

__global__ void scan_bsum(int* __restrict__ bsum, int nb)
{
    __shared__ int s[512];
    int t = threadIdx.x;
    int v = (t < nb) ? bsum[t] : 0;
    s[t] = v; __syncthreads();
    for (int d = 1; d < 512; d <<= 1) {
        int add = (t >= d) ? s[t - d] : 0;
        __syncthreads();
        s[t] += add;
        __syncthreads();
    }
    if (t < nb) bsum[t] = s[t] - v;
}

__global__ void scan_add(int* __restrict__ off, const int* __restrict__ bsum,
                         int* __restrict__ cur, int n)
{
    int g = blockIdx.x * 256 + threadIdx.x;
    if (g < n) { int o = off[g] + bsum[blockIdx.x]; off[g] = o; cur[g] = o; }
}

// also emits permuted src/dst arrays and the inverse permutation (einv)
__global__ void scatter_edges(const int* __restrict__ eidx, int* __restrict__ cur,
                              int* __restrict__ srcp, int* __restrict__ dstp,
                              int* __restrict__ einv)
{
    int e = blockIdx.x * 256 + threadIdx.x;
    if (e < NE) {
        int s = eidx[e], d = eidx[NE + e];
        int pos = atomicAdd(&cur[d + (e >= EHALF ? NN : 0)], 1);
        srcp[pos] = s;
        dstp[pos] = d;
        einv[e] = pos;
    }
}

// ---------------- edge_aggr: streaming gather + relu + aggregate ----------
// MT is already CSR-ordered -> sequential reads. srcp/dstp sequential.
// Thread owns column c; block owns NPB dst nodes; NT[dst] cached per run.
template<int ND, int NTS>
__global__ __launch_bounds__(128)
void edge_aggr(const __bf16* __restrict__ MT,     // [EHALF][112] CSR-ordered
               const int* __restrict__ srcp,      // [NE] permuted src
               const int* __restrict__ dstp,      // [NE] permuted dst
               const int* __restrict__ off,       // [NN2]
               const float* __restrict__ NT,      // [NN][NTS]
               const float* __restrict__ self,    // [NN][ND]
               float* __restrict__ aggr,          // [NN][ND]
               int phase, int blkd, int blks, int mode)
{
    __shared__ float accl[NPB * 112];
    __shared__ int lsrc[CHUNK], ldst[CHUNK];
    const int t = threadIdx.x;
    const int c = t;
    const int n0 = blockIdx.x * NPB;
    for (int i = t; i < NPB * 112; i += 128) accl[i] = 0.f;

    const int base = phase * NN + n0;
    const int p0 = off[base];
    const int p1 = (base + NPB == NN2) ? NE : off[base + NPB];
    const int ebase = phase * EHALF;

    float ndv = 0.f;
    int ndcur = -1;

    for (int pc = p0; pc < p1; pc += CHUNK) {
        const int cnt = min(CHUNK, p1 - pc);
        __syncthreads();   // accl init / previous chunk consumed
        for (int i = t; i < cnt; i += 128) {
            lsrc[i] = srcp[pc + i];
            ldst[i] = dstp[pc + i];
        }
        __syncthreads();
        for (int g = 0; g < cnt; g += GB) {
            int dd[GB], ss[GB];
            #pragma unroll
            for (int i = 0; i < GB; ++i) {
                int gi = g + i;
                bool ok = gi < cnt;
                dd[i] = ok ? ldst[gi] : -1;
                ss[i] = ok ? lsrc[gi] : 0;
            }
            if (c < ND) {
                float mtv[GB], ns[GB];
                #pragma unroll
                for (int i = 0; i < GB; ++i)
                    mtv[i] = (dd[i] >= 0)
                        ? (float)MT[(size_t)(pc + g + i - ebase) * 112 + c] : 0.f;
                #pragma unroll
                for (int i = 0; i < GB; ++i)
                    ns[i] = (dd[i] >= 0) ? NT[(size_t)ss[i] * NTS + blks + c] : 0.f;
                float run = 0.f; int rd = -1;
                #pragma unroll
                for (int i = 0; i < GB; ++i) {
                    if (dd[i] < 0) continue;            // wave-uniform
                    if (dd[i] != ndcur) {               // dst row cache (uniform)
                        ndv = NT[(size_t)dd[i] * NTS + blkd + c];
                        ndcur = dd[i];
                    }
                    float v = fmaxf(mtv[i] + ndv + ns[i], 0.f);
                    if (dd[i] == rd) run += v;
                    else {
                        if (rd >= 0) accl[(rd - n0) * 112 + c] += run;
                        rd = dd[i]; run = v;
                    }
                }
                if (rd >= 0) accl[(rd - n0) * 112 + c] += run;
            }
        }
    }
    __syncthreads();
    for (int i = t; i < NPB * ND; i += 128) {
        int n = i / ND, cc = i - n * ND;
        size_t g = (size_t)(n0 + n) * ND + cc;
        float val = accl[n * 112 + cc];
        aggr[g] = (mode == 0) ? (val + self[g]) : (aggr[g] + val);
    }
}

// ---------------- weight assembly (padded, 16B-aligned column blocks) -----
__global__ void assemble(const float* __restrict__ l1a, const float* __restrict__ l1ab,
                         const float* __restrict__ l1b, const float* __restrict__ l1bb,
                         const float* __restrict__ l2a, const float* __restrict__ l2ab,
                         const float* __restrict__ l2b, const float* __restrict__ l2bb,
                         float* __restrict__ W1, float* __restrict__ b1,
                         float* __restrict__ W2, float* __restrict__ b2)
{
    int i = blockIdx.x * 256 + threadIdx.x;
    if (i < 107 * 432) {
        int k = i / 432, c = i % 432;
        int q = c / 108, cc = c - q * 108;
        float v = 0.f;
        if (cc < 107) {
            if (q == 0)      v = l1a[k * 107 + cc];
            else if (q == 1) v = l1a[(207 + k) * 107 + cc];
            else if (q == 2) v = l1b[k * 107 + cc];
            else             v = l1b[(207 + k) * 107 + cc];
        }
        W1[i] = v;
    }
    if (i < 432) {
        int q = i / 108, cc = i - q * 108;
        b1[i] = (cc < 107) ? (q == 0 ? l1ab[cc] : (q == 3 ? l1bb[cc] : 0.f)) : 0.f;
    }
    if (i < 100 * 416) {
        int k = i / 416, c = i % 416;
        int q = c / 104, cc = c - q * 104;
        float v = 0.f;
        if (cc < 100) {
            if (q == 0)      v = l2a[k * 100 + cc];
            else if (q == 1) v = l2a[(200 + k) * 100 + cc];
            else if (q == 2) v = l2b[k * 100 + cc];
            else             v = l2b[(200 + k) * 100 + cc];
        }
        W2[i] = v;
    }
    if (i < 416) {
        int q = i / 104, cc = i - q * 104;
        b2[i] = (cc < 100) ? (q == 0 ? l2ab[cc] : (q == 3 ? l2bb[cc] : 0.f)) : 0.f;
    }
}

extern "C" void kernel_launch(void* const* d_in, const int* in_sizes, int n_in,
                              void* d_out, int out_size, void* d_ws, size_t ws_size,
                              hipStream_t stream)
{
    const float* x    = (const float*)d_in[0];
    const int*   eidx = (const int*)d_in[1];
    const float* eatt = (const float*)d_in[2];
    const float* l1aw = (const float*)d_in[3];
    const float* l1ab = (const float*)d_in[4];
    const float* l1bw = (const float*)d_in[5];
    const float* l1bb = (const float*)d_in[6];
    const float* m1w1 = (const float*)d_in[7];
    const float* m1b1 = (const float*)d_in[8];
    const float* m1w2 = (const float*)d_in[9];
    const float* m1b2 = (const float*)d_in[10];
    const float* l2aw = (const float*)d_in[11];
    const float* l2ab = (const float*)d_in[12];
    const float* l2bw = (const float*)d_in[13];
    const float* l2bb = (const float*)d_in[14];
    const float* m2w1 = (const float*)d_in[15];
    const float* m2b1 = (const float*)d_in[16];
    const float* m2w2 = (const float*)d_in[17];
    const float* m2b2 = (const float*)d_in[18];
    float* out = (float*)d_out;

    // workspace layout (4-byte units), ~226 MB
    float* ws   = (float*)d_ws;
    float* NT   = ws;                                   // 21,600,000
    float* bufA = NT + (size_t)50000 * 432;             // 5,350,000 (aggr)
    float* bufC = bufA + 5350000;                       // 5,000,000 (h)
    float* W1   = bufC + 5000000;                       // 46,224
    float* b1v  = W1 + 46224;                           // 432
    float* W2   = b1v + 432;                            // 41,600
    float* b2v  = W2 + 41600;                           // 416
    int*   off  = (int*)(b2v + 416);                    // 100,000
    int*   cur  = off + NN2;                            // 100,000
    int*   bsum = cur + NN2;                            // 512
    int*   srcp = bsum + 512;                           // 800,000
    int*   dstp = srcp + NE;                            // 800,000
    int*   einv = dstp + NE;                            // 800,000
    __bf16* MTb = (__bf16*)(einv + NE);                 // 400,000*112 bf16 = 89.6 MB
    float* bufB = (float*)MTb;                          // t1/t2 alias (disjoint lifetime)

    const int* dst = eidx + NE;

    assemble<<<181, 256, 0, stream>>>(l1aw, l1ab, l1bw, l1bb, l2aw, l2ab, l2bw, l2bb,
                                      W1, b1v, W2, b2v);

    // ---- CSR build (dst-sorted, per half; emits srcp/dstp/einv) ----
    zero_ints<<<(NN2 + 255) / 256, 256, 0, stream>>>(cur, NN2);
    count_edges<<<(NE + 255) / 256, 256, 0, stream>>>(dst, cur);
    scan_blocks<<<(NN2 + 255) / 256, 256, 0, stream>>>(cur, off, bsum, NN2);
    scan_bsum<<<1, 512, 0, stream>>>(bsum, (NN2 + 255) / 256);
    scan_add<<<(NN2 + 255) / 256, 256, 0, stream>>>(off, bsum, cur, NN2);
    scatter_edges<<<(NE + 255) / 256, 256, 0, stream>>>(eidx, cur, srcp, dstp, einv);

    const int AG = NN / NPB;   // 6250 aggr blocks

    // ---- conv1 ----
    mm_bf16<107, false><<<dim3(98, 7), 256, 0, stream>>>(x, W1, b1v, NT,
                                                         nullptr, 0, NN, 432, 432, 4, 0);
    mm_bf16<100, true><<<dim3(625, 2), 256, 0, stream>>>(eatt, l1aw + 107 * 107,
                                                         nullptr, MTb, einv, 0,
                                                         EHALF, 107, 112, 5, 0);
    edge_aggr<107, 432><<<AG, 128, 0, stream>>>(MTb, srcp, dstp, off, NT, x, bufA,
                                                0, 0, 108, 0);
    mm_bf16<100, true><<<dim3(625, 2), 256, 0, stream>>>(eatt + (size_t)EHALF * 100,
                                                         l1bw + 107 * 107,
                                                         nullptr, MTb, einv + EHALF, EHALF,
                                                         EHALF, 107, 112, 5, 0);
    edge_aggr<107, 432><<<AG, 128, 0, stream>>>(MTb, srcp, dstp, off, NT, x, bufA,
                                                1, 324, 216, 1);
    mm_bf16<107, false><<<dim3(98, 2), 256, 0, stream>>>(bufA, m1w1, m1b1, bufB,
                                                         nullptr, 0, NN, 100, 100, 4, 1);
    mm_bf16<100, false><<<dim3(98, 2), 256, 0, stream>>>(bufB, m1w2, m1b2, bufC,
                                                         nullptr, 0, NN, 100, 100, 4, 1);

    // ---- conv2 ----  (h in bufC)
    mm_bf16<100, false><<<dim3(98, 7), 256, 0, stream>>>(bufC, W2, b2v, NT,
                                                         nullptr, 0, NN, 416, 416, 4, 0);
    mm_bf16<100, true><<<dim3(625, 2), 256, 0, stream>>>(eatt, l2aw + 100 * 100,
                                                         nullptr, MTb, einv, 0,
                                                         EHALF, 100, 112, 5, 0);
    edge_aggr<100, 416><<<AG, 128, 0, stream>>>(MTb, srcp, dstp, off, NT, bufC, bufA,
                                                0, 0, 104, 0);
    mm_bf16<100, true><<<dim3(625, 2), 256, 0, stream>>>(eatt + (size_t)EHALF * 100,
                                                         l2bw + 100 * 100,
                                                         nullptr, MTb, einv + EHALF, EHALF,
                                                         EHALF, 100, 112, 5, 0);
    edge_aggr<100, 416><<<AG, 128, 0, stream>>>(MTb, srcp, dstp, off, NT, bufC, bufA,
                                                1, 312, 208, 1);
    mm_bf16<100, false><<<dim3(98, 1), 256, 0, stream>>>(bufA, m2w1, m2b1, bufB,
                                                         nullptr, 0, NN, 64, 64, 4, 1);
    mm_bf16<64, false><<<dim3(98, 2), 256, 0, stream>>>(bufB, m2w2, m2b2, out,
                                                        nullptr, 0, NN, 100, 100, 4, 0);
}

// Round 8
// 1590.121 us; speedup vs baseline: 1.4820x; 1.1616x over previous
//
#include <hip/hip_runtime.h>

// RuleGraphNet: 2x TripleConv(+mlp), N=50000 nodes, E=800000 edges.
// All matmuls via one bf16-MFMA template (mm_bf16). Edge mid-GEMM (MT) is
// stored CONTIGUOUS in natural edge order (coalesced wave stores); the
// aggregation kernel applies the CSR permutation on its (row-coalesced)
// MT reads instead. NT[dst] hoisted per run; LDS accumulate; self fused.

#define NN 50000
#define NE 800000
#define EHALF 400000
#define NN2 100000
#define NPB 8           // dst nodes per edge_aggr block
#define CHUNK 256       // edge slots staged per aggr iteration
#define GB 8            // edges per inner group

typedef __attribute__((ext_vector_type(4))) float  f32x4;
typedef __attribute__((ext_vector_type(8))) __bf16 bf16x8;
typedef __attribute__((ext_vector_type(4))) __bf16 bf16x4;

// ---------------- generic bf16 MFMA GEMM ----------------
// Out[M][ldo] = act(A[M][K] @ W[K][N] + bias); A/W fp32 in, bf16 compute.
// Block: 128 rows x 64 cols (col chunk = blockIdx.y), RT row-tiles per block.
// OBF16: bf16 output, stride ldo, cols guarded by ldo (pad cols hold zeros).
template<int K, bool OBF16>
__global__ __launch_bounds__(256)
void mm_bf16(const float* __restrict__ A, const float* __restrict__ W,
             const float* __restrict__ bias, void* __restrict__ Outp,
             int M, int N, int ldo, int RT, int relu)
{
    __shared__ __align__(16) __bf16 et[128 * 128];   // 32 KB A-tile, swizzled
    const int t = threadIdx.x;
    const int lane = t & 63, w = t >> 6;
    const int mh = w & 1, nh = w >> 1;
    const int l15 = lane & 15, l4 = lane >> 4;
    const int cb = blockIdx.y * 64;

    // B-fragments in registers (once per block)
    bf16x8 wf[2][4];
    const int colbase = cb + nh * 32 + l15;
    #pragma unroll
    for (int nt = 0; nt < 2; ++nt) {
        int col = colbase + nt * 16;
        #pragma unroll
        for (int ks = 0; ks < 4; ++ks) {
            bf16x8 f;
            #pragma unroll
            for (int j = 0; j < 8; ++j) {
                int k = ks * 32 + l4 * 8 + j;
                float v = (k < K && col < N) ? W[k * N + col] : 0.f;
                f[j] = (__bf16)v;
            }
            wf[nt][ks] = f;
        }
    }
    float bv[2] = {0.f, 0.f};
    if (bias) {
        #pragma unroll
        for (int nt = 0; nt < 2; ++nt) {
            int col = colbase + nt * 16;
            if (col < N) bv[nt] = bias[col];
        }
    }

    for (int it = 0; it < RT; ++it) {
        const int row0 = (blockIdx.x * RT + it) * 128;
        if (row0 >= M) break;
        __syncthreads();   // et reuse vs previous tile's reads
        if constexpr (K % 4 == 0) {
            constexpr int QK = K / 4;
            for (int i = t; i < 128 * QK; i += 256) {
                int row = i / QK, q = i - row * QK;
                int gr = row0 + row;
                float4 v = {0.f, 0.f, 0.f, 0.f};
                if (gr < M) v = *(const float4*)(A + (size_t)gr * K + q * 4);
                bf16x4 b;
                b[0] = (__bf16)v.x; b[1] = (__bf16)v.y;
                b[2] = (__bf16)v.z; b[3] = (__bf16)v.w;
                *(bf16x4*)(et + row * 128 + ((q * 4) ^ ((row & 7) << 3))) = b;
            }
            constexpr int QP = (128 - K) / 4;
            for (int i = t; i < 128 * QP; i += 256) {
                int row = i / QP, q = QK + (i - (i / QP) * QP);
                bf16x4 z;
                z[0] = (__bf16)0.f; z[1] = (__bf16)0.f;
                z[2] = (__bf16)0.f; z[3] = (__bf16)0.f;
                *(bf16x4*)(et + row * 128 + ((q * 4) ^ ((row & 7) << 3))) = z;
            }
        } else {
            for (int i = t; i < 128 * 128; i += 256) {
                int row = i >> 7, k = i & 127;
                int gr = row0 + row;
                float v = (k < K && gr < M) ? A[(size_t)gr * K + k] : 0.f;
                et[row * 128 + (k ^ ((row & 7) << 3))] = (__bf16)v;
            }
        }
        __syncthreads();

        f32x4 c[4][2] = {};
        #pragma unroll
        for (int ks = 0; ks < 4; ++ks) {
            #pragma unroll
            for (int mt = 0; mt < 4; ++mt) {
                int arow = mh * 64 + mt * 16 + l15;
                bf16x8 a = *(const bf16x8*)(et + arow * 128 +
                                            ((ks * 32 + l4 * 8) ^ ((l15 & 7) << 3)));
                c[mt][0] = __builtin_amdgcn_mfma_f32_16x16x32_bf16(a, wf[0][ks], c[mt][0], 0, 0, 0);
                c[mt][1] = __builtin_amdgcn_mfma_f32_16x16x32_bf16(a, wf[1][ks], c[mt][1], 0, 0, 0);
            }
        }

        #pragma unroll
        for (int mt = 0; mt < 4; ++mt) {
            #pragma unroll
            for (int nt = 0; nt < 2; ++nt) {
                int col = colbase + nt * 16;
                #pragma unroll
                for (int r = 0; r < 4; ++r) {
                    int row = row0 + mh * 64 + mt * 16 + l4 * 4 + r;
                    if constexpr (OBF16) {
                        if (row < M && col < ldo)
                            ((__bf16*)Outp)[(size_t)row * ldo + col] = (__bf16)c[mt][nt][r];
                    } else {
                        if (row < M && col < N) {
                            float v = c[mt][nt][r] + bv[nt];
                            if (relu) v = fmaxf(v, 0.f);
                            ((float*)Outp)[(size_t)row * ldo + col] = v;
                        }
                    }
                }
            }
        }
    }
}

// ---------------- CSR build (edges sorted by dst, per half) ----------------
__global__ void zero_ints(int* __restrict__ p, int n)
{
    int i = blockIdx.x * 256 + threadIdx.x;
    if (i < n) p[i] = 0;
}

__global__ void count_edges(const int* __restrict__ dst, int* __restrict__ cnt)
{
    int e = blockIdx.x * 256 + threadIdx.x;
    if (e < NE) atomicAdd(&cnt[dst[e] + (e >= EHALF ? NN : 0)], 1);
}

__global__ void scan_blocks(const int* __restrict__ cnt, int* __restrict__ off,
                            int* __restrict__ bsum, int n)
{
    __shared__ int s[256];
    int t = threadIdx.x, g = blockIdx.x * 256 + t;
    int v = (g < n) ? cnt[g] : 0;
    s[t] = v; __syncthreads();
    for (int d = 1; d < 256; d <<= 1) {
        int add = (t >= d) ? s[t - d] : 0;
        __syncthreads();
        s[t] += add;
        __syncthreads();
    }
    if (g < n) off[g] = s[t] - v;
    if (t == 255) bsum[blockIdx.x] = s[255];
}

__global__ void scan_bsum(int* __restrict__ bsum, int nb)
{
    __shared__ int s[512];
    int t = threadIdx.x;
    int v = (t < nb) ? bsum[t] : 0;
    s[t] = v; __syncthreads();
    for (int d = 1; d < 512; d <<= 1) {
        int add = (t >= d) ? s[t - d] : 0;
        __syncthreads();
        s[t] += add;
        __syncthreads();
    }
    if (t < nb) bsum[t] = s[t] - v;
}

__global__ void scan_add(int* __restrict__ off, const int* __restrict__ bsum,
                         int* __restrict__ cur, int n)
{
    int g = blockIdx.x * 256 + threadIdx.x;
    if (g < n) { int o = off[g] + bsum[blockIdx.x]; off[g] = o; cur[g] = o; }
}

// emits dst-sorted permutation + permuted src/dst arrays
__global__ void scatter_edges(const int* __restrict__ eidx, int* __restrict__ cur,
                              int* __restrict__ perm,
                              int* __restrict__ srcp, int* __restrict__ dstp)
{
    int e = blockIdx.x * 256 + threadIdx.x;
    if (e < NE) {
        int s = eidx[e], d = eidx[NE + e];
        int pos = atomicAdd(&cur[d + (e >= EHALF ? NN : 0)], 1);
        perm[pos] = e;
        srcp[pos] = s;
        dstp[pos] = d;
    }
}

// ---------------- edge_aggr: gather + relu + aggregate ----------
// MT contiguous in edge order; row picked via perm (row reads stay coalesced
// per wave). srcp/dstp sequential. Thread owns column c; block owns NPB dst
// nodes; NT[dst] cached per run; thread-exclusive cols -> plain LDS +=.
template<int ND, int NTS>
__global__ __launch_bounds__(128)
void edge_aggr(const __bf16* __restrict__ MT,     // [EHALF][112] edge order
               const int* __restrict__ perm,      // [NE] sorted pos -> edge id
               const int* __restrict__ srcp,      // [NE] permuted src
               const int* __restrict__ dstp,      // [NE] permuted dst
               const int* __restrict__ off,       // [NN2]
               const float* __restrict__ NT,      // [NN][NTS]
               const float* __restrict__ self,    // [NN][ND]
               float* __restrict__ aggr,          // [NN][ND]
               int phase, int blkd, int blks, int mode)
{
    __shared__ float accl[NPB * 112];
    __shared__ int lee[CHUNK], lsrc[CHUNK], ldst[CHUNK];
    const int t = threadIdx.x;
    const int c = t;
    const int n0 = blockIdx.x * NPB;
    for (int i = t; i < NPB * 112; i += 128) accl[i] = 0.f;

    const int base = phase * NN + n0;
    const int p0 = off[base];
    const int p1 = (base + NPB == NN2) ? NE : off[base + NPB];
    const int ebase = phase * EHALF;

    float ndv = 0.f;
    int ndcur = -1;

    for (int pc = p0; pc < p1; pc += CHUNK) {
        const int cnt = min(CHUNK, p1 - pc);
        __syncthreads();   // accl init / previous chunk consumed
        for (int i = t; i < cnt; i += 128) {
            lee[i]  = perm[pc + i] - ebase;
            lsrc[i] = srcp[pc + i];
            ldst[i] = dstp[pc + i];
        }
        __syncthreads();
        for (int g = 0; g < cnt; g += GB) {
            int dd[GB], ss[GB], ee[GB];
            #pragma unroll
            for (int i = 0; i < GB; ++i) {
                int gi = g + i;
                bool ok = gi < cnt;
                dd[i] = ok ? ldst[gi] : -1;
                ss[i] = ok ? lsrc[gi] : 0;
                ee[i] = ok ? lee[gi] : 0;
            }
            if (c < ND) {
                float mtv[GB], ns[GB];
                #pragma unroll
                for (int i = 0; i < GB; ++i)
                    mtv[i] = (dd[i] >= 0) ? (float)MT[(size_t)ee[i] * 112 + c] : 0.f;
                #pragma unroll
                for (int i = 0; i < GB; ++i)
                    ns[i] = (dd[i] >= 0) ? NT[(size_t)ss[i] * NTS + blks + c] : 0.f;
                float run = 0.f; int rd = -1;
                #pragma unroll
                for (int i = 0; i < GB; ++i) {
                    if (dd[i] < 0) continue;            // wave-uniform
                    if (dd[i] != ndcur) {               // dst row cache (uniform)
                        ndv = NT[(size_t)dd[i] * NTS + blkd + c];
                        ndcur = dd[i];
                    }
                    float v = fmaxf(mtv[i] + ndv + ns[i], 0.f);
                    if (dd[i] == rd) run += v;
                    else {
                        if (rd >= 0) accl[(rd - n0) * 112 + c] += run;
                        rd = dd[i]; run = v;
                    }
                }
                if (rd >= 0) accl[(rd - n0) * 112 + c] += run;
            }
        }
    }
    __syncthreads();
    for (int i = t; i < NPB * ND; i += 128) {
        int n = i / ND, cc = i - n * ND;
        size_t g = (size_t)(n0 + n) * ND + cc;
        float val = accl[n * 112 + cc];
        aggr[g] = (mode == 0) ? (val + self[g]) : (aggr[g] + val);
    }
}

// ---------------- weight assembly (padded, 16B-aligned column blocks) -----
__global__ void assemble(const float* __restrict__ l1a, const float* __restrict__ l1ab,
                         const float* __restrict__ l1b, const float* __restrict__ l1bb,
                         const float* __restrict__ l2a, const float* __restrict__ l2ab,
                         const float* __restrict__ l2b, const float* __restrict__ l2bb,
                         float* __restrict__ W1, float* __restrict__ b1,
                         float* __restrict__ W2, float* __restrict__ b2)
{
    int i = blockIdx.x * 256 + threadIdx.x;
    if (i < 107 * 432) {
        int k = i / 432, c = i % 432;
        int q = c / 108, cc = c - q * 108;
        float v = 0.f;
        if (cc < 107) {
            if (q == 0)      v = l1a[k * 107 + cc];
            else if (q == 1) v = l1a[(207 + k) * 107 + cc];
            else if (q == 2) v = l1b[k * 107 + cc];
            else             v = l1b[(207 + k) * 107 + cc];
        }
        W1[i] = v;
    }
    if (i < 432) {
        int q = i / 108, cc = i - q * 108;
        b1[i] = (cc < 107) ? (q == 0 ? l1ab[cc] : (q == 3 ? l1bb[cc] : 0.f)) : 0.f;
    }
    if (i < 100 * 416) {
        int k = i / 416, c = i % 416;
        int q = c / 104, cc = c - q * 104;
        float v = 0.f;
        if (cc < 100) {
            if (q == 0)      v = l2a[k * 100 + cc];
            else if (q == 1) v = l2a[(200 + k) * 100 + cc];
            else if (q == 2) v = l2b[k * 100 + cc];
            else             v = l2b[(200 + k) * 100 + cc];
        }
        W2[i] = v;
    }
    if (i < 416) {
        int q = i / 104, cc = i - q * 104;
        b2[i] = (cc < 100) ? (q == 0 ? l2ab[cc] : (q == 3 ? l2bb[cc] : 0.f)) : 0.f;
    }
}

extern "C" void kernel_launch(void* const* d_in, const int* in_sizes, int n_in,
                              void* d_out, int out_size, void* d_ws, size_t ws_size,
                              hipStream_t stream)
{
    const float* x    = (const float*)d_in[0];
    const int*   eidx = (const int*)d_in[1];
    const float* eatt = (const float*)d_in[2];
    const float* l1aw = (const float*)d_in[3];
    const float* l1ab = (const float*)d_in[4];
    const float* l1bw = (const float*)d_in[5];
    const float* l1bb = (const float*)d_in[6];
    const float* m1w1 = (const float*)d_in[7];
    const float* m1b1 = (const float*)d_in[8];
    const float* m1w2 = (const float*)d_in[9];
    const float* m1b2 = (const float*)d_in[10];
    const float* l2aw = (const float*)d_in[11];
    const float* l2ab = (const float*)d_in[12];
    const float* l2bw = (const float*)d_in[13];
    const float* l2bb = (const float*)d_in[14];
    const float* m2w1 = (const float*)d_in[15];
    const float* m2b1 = (const float*)d_in[16];
    const float* m2w2 = (const float*)d_in[17];
    const float* m2b2 = (const float*)d_in[18];
    float* out = (float*)d_out;

    // workspace layout (4-byte units), ~229 MB
    float* ws   = (float*)d_ws;
    float* NT   = ws;                                   // 21,600,000
    float* bufA = NT + (size_t)50000 * 432;             // 5,350,000 (aggr)
    float* bufC = bufA + 5350000;                       // 5,000,000 (h)
    float* W1   = bufC + 5000000;                       // 46,224
    float* b1v  = W1 + 46224;                           // 432
    float* W2   = b1v + 432;                            // 41,600
    float* b2v  = W2 + 41600;                           // 416
    int*   off  = (int*)(b2v + 416);                    // 100,000
    int*   cur  = off + NN2;                            // 100,000
    int*   bsum = cur + NN2;                            // 512
    int*   perm = bsum + 512;                           // 800,000
    int*   srcp = perm + NE;                            // 800,000
    int*   dstp = srcp + NE;                            // 800,000
    __bf16* MTb = (__bf16*)(dstp + NE);                 // 400,000*112 bf16 = 89.6 MB
    float* bufB = (float*)MTb;                          // t1/t2 alias (disjoint lifetime)

    const int* dst = eidx + NE;

    assemble<<<181, 256, 0, stream>>>(l1aw, l1ab, l1bw, l1bb, l2aw, l2ab, l2bw, l2bb,
                                      W1, b1v, W2, b2v);

    // ---- CSR build (dst-sorted, per half; emits perm/srcp/dstp) ----
    zero_ints<<<(NN2 + 255) / 256, 256, 0, stream>>>(cur, NN2);
    count_edges<<<(NE + 255) / 256, 256, 0, stream>>>(dst, cur);
    scan_blocks<<<(NN2 + 255) / 256, 256, 0, stream>>>(cur, off, bsum, NN2);
    scan_bsum<<<1, 512, 0, stream>>>(bsum, (NN2 + 255) / 256);
    scan_add<<<(NN2 + 255) / 256, 256, 0, stream>>>(off, bsum, cur, NN2);
    scatter_edges<<<(NE + 255) / 256, 256, 0, stream>>>(eidx, cur, perm, srcp, dstp);

    const int AG = NN / NPB;   // 6250 aggr blocks

    // ---- conv1 ----
    mm_bf16<107, false><<<dim3(98, 7), 256, 0, stream>>>(x, W1, b1v, NT,
                                                         NN, 432, 432, 4, 0);
    mm_bf16<100, true><<<dim3(625, 2), 256, 0, stream>>>(eatt, l1aw + 107 * 107,
                                                         nullptr, MTb,
                                                         EHALF, 107, 112, 5, 0);
    edge_aggr<107, 432><<<AG, 128, 0, stream>>>(MTb, perm, srcp, dstp, off, NT, x, bufA,
                                                0, 0, 108, 0);
    mm_bf16<100, true><<<dim3(625, 2), 256, 0, stream>>>(eatt + (size_t)EHALF * 100,
                                                         l1bw + 107 * 107,
                                                         nullptr, MTb,
                                                         EHALF, 107, 112, 5, 0);
    edge_aggr<107, 432><<<AG, 128, 0, stream>>>(MTb, perm, srcp, dstp, off, NT, x, bufA,
                                                1, 324, 216, 1);
    mm_bf16<107, false><<<dim3(98, 2), 256, 0, stream>>>(bufA, m1w1, m1b1, bufB,
                                                         NN, 100, 100, 4, 1);
    mm_bf16<100, false><<<dim3(98, 2), 256, 0, stream>>>(bufB, m1w2, m1b2, bufC,
                                                         NN, 100, 100, 4, 1);

    // ---- conv2 ----  (h in bufC)
    mm_bf16<100, false><<<dim3(98, 7), 256, 0, stream>>>(bufC, W2, b2v, NT,
                                                         NN, 416, 416, 4, 0);
    mm_bf16<100, true><<<dim3(625, 2), 256, 0, stream>>>(eatt, l2aw + 100 * 100,
                                                         nullptr, MTb,
                                                         EHALF, 100, 112, 5, 0);
    edge_aggr<100, 416><<<AG, 128, 0, stream>>>(MTb, perm, srcp, dstp, off, NT, bufC, bufA,
                                                0, 0, 104, 0);
    mm_bf16<100, true><<<dim3(625, 2), 256, 0, stream>>>(eatt + (size_t)EHALF * 100,
                                                         l2bw + 100 * 100,
                                                         nullptr, MTb,
                                                         EHALF, 100, 112, 5, 0);
    edge_aggr<100, 416><<<AG, 128, 0, stream>>>(MTb, perm, srcp, dstp, off, NT, bufC, bufA,
                                                1, 312, 208, 1);
    mm_bf16<100, false><<<dim3(98, 1), 256, 0, stream>>>(bufA, m2w1, m2b1, bufB,
                                                         NN, 64, 64, 4, 1);
    mm_bf16<64, false><<<dim3(98, 2), 256, 0, stream>>>(bufB, m2w2, m2b2, out,
                                                        NN, 100, 100, 4, 0);
}

// Round 9
// 1461.549 us; speedup vs baseline: 1.6124x; 1.0880x over previous
//
#include <hip/hip_runtime.h>

// RuleGraphNet: 2x TripleConv(+mlp), N=50000 nodes, E=800000 edges.
// All matmuls via one bf16-MFMA template (mm_bf16). Edge mid-GEMM (MT) stored
// contiguous in edge order. Aggregation: wave owns 2 dst nodes (exclusive CSR
// ranges), lane owns a column PAIR -> register accumulation, no LDS/atomics;
// packed int2{edge,src} index stream; NT[dst] hoisted per node; self fused.

#define NN 50000
#define NE 800000
#define EHALF 400000
#define NN2 100000
#define GB 8            // edges batched per gather group

typedef __attribute__((ext_vector_type(4))) float  f32x4;
typedef __attribute__((ext_vector_type(8))) __bf16 bf16x8;
typedef __attribute__((ext_vector_type(4))) __bf16 bf16x4;

__device__ __forceinline__ float bf16lo(unsigned u) {
    union { unsigned u; float f; } c; c.u = u << 16; return c.f;
}
__device__ __forceinline__ float bf16hi(unsigned u) {
    union { unsigned u; float f; } c; c.u = u & 0xffff0000u; return c.f;
}

// ---------------- generic bf16 MFMA GEMM ----------------
// Out[M][ldo] = act(A[M][K] @ W[K][N] + bias); A/W fp32 in, bf16 compute.
// Block: 128 rows x 64 cols (col chunk = blockIdx.y), RT row-tiles per block.
// OBF16: bf16 output, stride ldo, cols guarded by ldo (pad cols hold zeros).
template<int K, bool OBF16>
__global__ __launch_bounds__(256)
void mm_bf16(const float* __restrict__ A, const float* __restrict__ W,
             const float* __restrict__ bias, void* __restrict__ Outp,
             int M, int N, int ldo, int RT, int relu)
{
    __shared__ __align__(16) __bf16 et[128 * 128];   // 32 KB A-tile, swizzled
    const int t = threadIdx.x;
    const int lane = t & 63, w = t >> 6;
    const int mh = w & 1, nh = w >> 1;
    const int l15 = lane & 15, l4 = lane >> 4;
    const int cb = blockIdx.y * 64;

    // B-fragments in registers (once per block)
    bf16x8 wf[2][4];
    const int colbase = cb + nh * 32 + l15;
    #pragma unroll
    for (int nt = 0; nt < 2; ++nt) {
        int col = colbase + nt * 16;
        #pragma unroll
        for (int ks = 0; ks < 4; ++ks) {
            bf16x8 f;
            #pragma unroll
            for (int j = 0; j < 8; ++j) {
                int k = ks * 32 + l4 * 8 + j;
                float v = (k < K && col < N) ? W[k * N + col] : 0.f;
                f[j] = (__bf16)v;
            }
            wf[nt][ks] = f;
        }
    }
    float bv[2] = {0.f, 0.f};
    if (bias) {
        #pragma unroll
        for (int nt = 0; nt < 2; ++nt) {
            int col = colbase + nt * 16;
            if (col < N) bv[nt] = bias[col];
        }
    }

    for (int it = 0; it < RT; ++it) {
        const int row0 = (blockIdx.x * RT + it) * 128;
        if (row0 >= M) break;
        __syncthreads();   // et reuse vs previous tile's reads
        if constexpr (K % 4 == 0) {
            constexpr int QK = K / 4;
            for (int i = t; i < 128 * QK; i += 256) {
                int row = i / QK, q = i - row * QK;
                int gr = row0 + row;
                float4 v = {0.f, 0.f, 0.f, 0.f};
                if (gr < M) v = *(const float4*)(A + (size_t)gr * K + q * 4);
                bf16x4 b;
                b[0] = (__bf16)v.x; b[1] = (__bf16)v.y;
                b[2] = (__bf16)v.z; b[3] = (__bf16)v.w;
                *(bf16x4*)(et + row * 128 + ((q * 4) ^ ((row & 7) << 3))) = b;
            }
            constexpr int QP = (128 - K) / 4;
            for (int i = t; i < 128 * QP; i += 256) {
                int row = i / QP, q = QK + (i - (i / QP) * QP);
                bf16x4 z;
                z[0] = (__bf16)0.f; z[1] = (__bf16)0.f;
                z[2] = (__bf16)0.f; z[3] = (__bf16)0.f;
                *(bf16x4*)(et + row * 128 + ((q * 4) ^ ((row & 7) << 3))) = z;
            }
        } else {
            for (int i = t; i < 128 * 128; i += 256) {
                int row = i >> 7, k = i & 127;
                int gr = row0 + row;
                float v = (k < K && gr < M) ? A[(size_t)gr * K + k] : 0.f;
                et[row * 128 + (k ^ ((row & 7) << 3))] = (__bf16)v;
            }
        }
        __syncthreads();

        f32x4 c[4][2] = {};
        #pragma unroll
        for (int ks = 0; ks < 4; ++ks) {
            #pragma unroll
            for (int mt = 0; mt < 4; ++mt) {
                int arow = mh * 64 + mt * 16 + l15;
                bf16x8 a = *(const bf16x8*)(et + arow * 128 +
                                            ((ks * 32 + l4 * 8) ^ ((l15 & 7) << 3)));
                c[mt][0] = __builtin_amdgcn_mfma_f32_16x16x32_bf16(a, wf[0][ks], c[mt][0], 0, 0, 0);
                c[mt][1] = __builtin_amdgcn_mfma_f32_16x16x32_bf16(a, wf[1][ks], c[mt][1], 0, 0, 0);
            }
        }

        #pragma unroll
        for (int mt = 0; mt < 4; ++mt) {
            #pragma unroll
            for (int nt = 0; nt < 2; ++nt) {
                int col = colbase + nt * 16;
                #pragma unroll
                for (int r = 0; r < 4; ++r) {
                    int row = row0 + mh * 64 + mt * 16 + l4 * 4 + r;
                    if constexpr (OBF16) {
                        if (row < M && col < ldo)
                            ((__bf16*)Outp)[(size_t)row * ldo + col] = (__bf16)c[mt][nt][r];
                    } else {
                        if (row < M && col < N) {
                            float v = c[mt][nt][r] + bv[nt];
                            if (relu) v = fmaxf(v, 0.f);
                            ((float*)Outp)[(size_t)row * ldo + col] = v;
                        }
                    }
                }
            }
        }
    }
}

// ---------------- CSR build (edges sorted by dst, per half) ----------------
__global__ void zero_ints(int* __restrict__ p, int n)
{
    int i = blockIdx.x * 256 + threadIdx.x;
    if (i < n) p[i] = 0;
}

__global__ void count_edges(const int* __restrict__ dst, int* __restrict__ cnt)
{
    int e = blockIdx.x * 256 + threadIdx.x;
    if (e < NE) atomicAdd(&cnt[dst[e] + (e >= EHALF ? NN : 0)], 1);
}

__global__ void scan_blocks(const int* __restrict__ cnt, int* __restrict__ off,
                            int* __restrict__ bsum, int n)
{
    __shared__ int s[256];
    int t = threadIdx.x, g = blockIdx.x * 256 + t;
    int v = (g < n) ? cnt[g] : 0;
    s[t] = v; __syncthreads();
    for (int d = 1; d < 256; d <<= 1) {
        int add = (t >= d) ? s[t - d] : 0;
        __syncthreads();
        s[t] += add;
        __syncthreads();
    }
    if (g < n) off[g] = s[t] - v;
    if (t == 255) bsum[blockIdx.x] = s[255];
}

__global__ void scan_bsum(int* __restrict__ bsum, int nb)
{
    __shared__ int s[512];
    int t = threadIdx.x;
    int v = (t < nb) ? bsum[t] : 0;
    s[t] = v; __syncthreads();
    for (int d = 1; d < 512; d <<= 1) {
        int add = (t >= d) ? s[t - d] : 0;
        __syncthreads();
        s[t] += add;
        __syncthreads();
    }
    if (t < nb) bsum[t] = s[t] - v;
}

__global__ void scan_add(int* __restrict__ off, const int* __restrict__ bsum,
                         int* __restrict__ cur, int n)
{
    int g = blockIdx.x * 256 + threadIdx.x;
    if (g < n) { int o = off[g] + bsum[blockIdx.x]; off[g] = o; cur[g] = o; }
}

// emits packed {edge, src} per sorted position
__global__ void scatter_edges(const int* __restrict__ eidx, int* __restrict__ cur,
                              int2* __restrict__ epk)
{
    int e = blockIdx.x * 256 + threadIdx.x;
    if (e < NE) {
        int s = eidx[e], d = eidx[NE + e];
        int pos = atomicAdd(&cur[d + (e >= EHALF ? NN : 0)], 1);
        int2 v; v.x = e; v.y = s;
        epk[pos] = v;
    }
}

// ---------------- edge_aggr: register-accumulated aggregation ----------
// Wave owns 2 consecutive dst nodes (exclusive CSR ranges). Lane owns column
// pair (2*lane, 2*lane+1): per edge one u32 MT load + one float2 NT[src] load.
// NT[dst] loaded once per node. Pad cols (>=ND) in MT/NT are zeros, so loads
// are unguarded; only writes are guarded. mode0: aggr=acc+self; mode1: aggr+=acc.
template<int ND, int NTS>
__global__ __launch_bounds__(256)
void edge_aggr(const __bf16* __restrict__ MT,     // [EHALF][112] edge order
               const int2* __restrict__ epk,      // [NE] {edge, src} sorted
               const int* __restrict__ off,       // [NN2]
               const float* __restrict__ NT,      // [NN][NTS]
               const float* __restrict__ self,    // [NN][ND]
               float* __restrict__ aggr,          // [NN][ND]
               int phase, int blkd, int blks, int mode)
{
    const int t = threadIdx.x;
    const int lane = t & 63, wv = t >> 6;
    const int c0 = lane * 2;
    const bool a0 = c0 < ND, a1 = c0 + 1 < ND;
    const int wid = blockIdx.x * 4 + wv;
    const int ebase = phase * EHALF;

    #pragma unroll
    for (int ni = 0; ni < 2; ++ni) {
        const int n = wid * 2 + ni;                // n < NN by grid construction
        const int idx = phase * NN + n;
        const int pb = off[idx];
        const int pe = (idx + 1 == NN2) ? NE : off[idx + 1];

        float nd0 = 0.f, nd1 = 0.f;
        if (a0) {
            float2 nd = *(const float2*)(NT + (size_t)n * NTS + blkd + c0);
            nd0 = nd.x; nd1 = nd.y;
        }
        float acc0 = 0.f, acc1 = 0.f;

        for (int p = pb; p < pe; p += GB) {
            int ee[GB], ss[GB];
            #pragma unroll
            for (int i = 0; i < GB; ++i) {
                int pp = p + i;
                if (pp < pe) { int2 pk = epk[pp]; ee[i] = pk.x; ss[i] = pk.y; }
                else         { ee[i] = -1; ss[i] = 0; }
            }
            unsigned mtw[GB]; float2 ns[GB];
            #pragma unroll
            for (int i = 0; i < GB; ++i) {
                mtw[i] = 0u; ns[i].x = 0.f; ns[i].y = 0.f;
                if (ee[i] >= 0 && a0) {
                    mtw[i] = *(const unsigned*)(MT + (size_t)(ee[i] - ebase) * 112 + c0);
                    ns[i] = *(const float2*)(NT + (size_t)ss[i] * NTS + blks + c0);
                }
            }
            #pragma unroll
            for (int i = 0; i < GB; ++i) {
                if (ee[i] < 0) continue;           // wave-uniform
                acc0 += fmaxf(bf16lo(mtw[i]) + nd0 + ns[i].x, 0.f);
                acc1 += fmaxf(bf16hi(mtw[i]) + nd1 + ns[i].y, 0.f);
            }
        }

        const size_t g0 = (size_t)n * ND + c0;
        if (a0) aggr[g0]     = acc0 + (mode == 0 ? self[g0]     : aggr[g0]);
        if (a1) aggr[g0 + 1] = acc1 + (mode == 0 ? self[g0 + 1] : aggr[g0 + 1]);
    }
}

// ---------------- weight assembly (padded, 16B-aligned column blocks) -----
__global__ void assemble(const float* __restrict__ l1a, const float* __restrict__ l1ab,
                         const float* __restrict__ l1b, const float* __restrict__ l1bb,
                         const float* __restrict__ l2a, const float* __restrict__ l2ab,
                         const float* __restrict__ l2b, const float* __restrict__ l2bb,
                         float* __restrict__ W1, float* __restrict__ b1,
                         float* __restrict__ W2, float* __restrict__ b2)
{
    int i = blockIdx.x * 256 + threadIdx.x;
    if (i < 107 * 432) {
        int k = i / 432, c = i % 432;
        int q = c / 108, cc = c - q * 108;
        float v = 0.f;
        if (cc < 107) {
            if (q == 0)      v = l1a[k * 107 + cc];
            else if (q == 1) v = l1a[(207 + k) * 107 + cc];
            else if (q == 2) v = l1b[k * 107 + cc];
            else             v = l1b[(207 + k) * 107 + cc];
        }
        W1[i] = v;
    }
    if (i < 432) {
        int q = i / 108, cc = i - q * 108;
        b1[i] = (cc < 107) ? (q == 0 ? l1ab[cc] : (q == 3 ? l1bb[cc] : 0.f)) : 0.f;
    }
    if (i < 100 * 416) {
        int k = i / 416, c = i % 416;
        int q = c / 104, cc = c - q * 104;
        float v = 0.f;
        if (cc < 100) {
            if (q == 0)      v = l2a[k * 100 + cc];
            else if (q == 1) v = l2a[(200 + k) * 100 + cc];
            else if (q == 2) v = l2b[k * 100 + cc];
            else             v = l2b[(200 + k) * 100 + cc];
        }
        W2[i] = v;
    }
    if (i < 416) {
        int q = i / 104, cc = i - q * 104;
        b2[i] = (cc < 100) ? (q == 0 ? l2ab[cc] : (q == 3 ? l2bb[cc] : 0.f)) : 0.f;
    }
}

extern "C" void kernel_launch(void* const* d_in, const int* in_sizes, int n_in,
                              void* d_out, int out_size, void* d_ws, size_t ws_size,
                              hipStream_t stream)
{
    const float* x    = (const float*)d_in[0];
    const int*   eidx = (const int*)d_in[1];
    const float* eatt = (const float*)d_in[2];
    const float* l1aw = (const float*)d_in[3];
    const float* l1ab = (const float*)d_in[4];
    const float* l1bw = (const float*)d_in[5];
    const float* l1bb = (const float*)d_in[6];
    const float* m1w1 = (const float*)d_in[7];
    const float* m1b1 = (const float*)d_in[8];
    const float* m1w2 = (const float*)d_in[9];
    const float* m1b2 = (const float*)d_in[10];
    const float* l2aw = (const float*)d_in[11];
    const float* l2ab = (const float*)d_in[12];
    const float* l2bw = (const float*)d_in[13];
    const float* l2bb = (const float*)d_in[14];
    const float* m2w1 = (const float*)d_in[15];
    const float* m2b1 = (const float*)d_in[16];
    const float* m2w2 = (const float*)d_in[17];
    const float* m2b2 = (const float*)d_in[18];
    float* out = (float*)d_out;

    // workspace layout (4-byte units), ~225 MB
    float* ws   = (float*)d_ws;
    float* NT   = ws;                                   // 21,600,000
    float* bufA = NT + (size_t)50000 * 432;             // 5,350,000 (aggr)
    float* bufC = bufA + 5350000;                       // 5,000,000 (h)
    float* W1   = bufC + 5000000;                       // 46,224
    float* b1v  = W1 + 46224;                           // 432
    float* W2   = b1v + 432;                            // 41,600
    float* b2v  = W2 + 41600;                           // 416
    int*   off  = (int*)(b2v + 416);                    // 100,000
    int*   cur  = off + NN2;                            // 100,000
    int*   bsum = cur + NN2;                            // 512
    int2*  epk  = (int2*)(bsum + 512);                  // 800,000 int2 (8B-aligned)
    __bf16* MTb = (__bf16*)(epk + NE);                  // 400,000*112 bf16 = 89.6 MB
    float* bufB = (float*)MTb;                          // t1/t2 alias (disjoint lifetime)

    const int* dst = eidx + NE;

    assemble<<<181, 256, 0, stream>>>(l1aw, l1ab, l1bw, l1bb, l2aw, l2ab, l2bw, l2bb,
                                      W1, b1v, W2, b2v);

    // ---- CSR build (dst-sorted, per half; emits packed epk) ----
    zero_ints<<<(NN2 + 255) / 256, 256, 0, stream>>>(cur, NN2);
    count_edges<<<(NE + 255) / 256, 256, 0, stream>>>(dst, cur);
    scan_blocks<<<(NN2 + 255) / 256, 256, 0, stream>>>(cur, off, bsum, NN2);
    scan_bsum<<<1, 512, 0, stream>>>(bsum, (NN2 + 255) / 256);
    scan_add<<<(NN2 + 255) / 256, 256, 0, stream>>>(off, bsum, cur, NN2);
    scatter_edges<<<(NE + 255) / 256, 256, 0, stream>>>(eidx, cur, epk);

    const int AG = NN / 8;   // 6250 blocks: 4 waves x 2 nodes each

    // ---- conv1 ----
    mm_bf16<107, false><<<dim3(98, 7), 256, 0, stream>>>(x, W1, b1v, NT,
                                                         NN, 432, 432, 4, 0);
    mm_bf16<100, true><<<dim3(1042, 2), 256, 0, stream>>>(eatt, l1aw + 107 * 107,
                                                          nullptr, MTb,
                                                          EHALF, 107, 112, 3, 0);
    edge_aggr<107, 432><<<AG, 256, 0, stream>>>(MTb, epk, off, NT, x, bufA,
                                                0, 0, 108, 0);
    mm_bf16<100, true><<<dim3(1042, 2), 256, 0, stream>>>(eatt + (size_t)EHALF * 100,
                                                          l1bw + 107 * 107,
                                                          nullptr, MTb,
                                                          EHALF, 107, 112, 3, 0);
    edge_aggr<107, 432><<<AG, 256, 0, stream>>>(MTb, epk, off, NT, x, bufA,
                                                1, 324, 216, 1);
    mm_bf16<107, false><<<dim3(98, 2), 256, 0, stream>>>(bufA, m1w1, m1b1, bufB,
                                                         NN, 100, 100, 4, 1);
    mm_bf16<100, false><<<dim3(98, 2), 256, 0, stream>>>(bufB, m1w2, m1b2, bufC,
                                                         NN, 100, 100, 4, 1);

    // ---- conv2 ----  (h in bufC)
    mm_bf16<100, false><<<dim3(98, 7), 256, 0, stream>>>(bufC, W2, b2v, NT,
                                                         NN, 416, 416, 4, 0);
    mm_bf16<100, true><<<dim3(1042, 2), 256, 0, stream>>>(eatt, l2aw + 100 * 100,
                                                          nullptr, MTb,
                                                          EHALF, 100, 112, 3, 0);
    edge_aggr<100, 416><<<AG, 256, 0, stream>>>(MTb, epk, off, NT, bufC, bufA,
                                                0, 0, 104, 0);
    mm_bf16<100, true><<<dim3(1042, 2), 256, 0, stream>>>(eatt + (size_t)EHALF * 100,
                                                          l2bw + 100 * 100,
                                                          nullptr, MTb,
                                                          EHALF, 100, 112, 3, 0);
    edge_aggr<100, 416><<<AG, 256, 0, stream>>>(MTb, epk, off, NT, bufC, bufA,
                                                1, 312, 208, 1);
    mm_bf16<100, false><<<dim3(98, 1), 256, 0, stream>>>(bufA, m2w1, m2b1, bufB,
                                                         NN, 64, 64, 4, 1);
    mm_bf16<64, false><<<dim3(98, 2), 256, 0, stream>>>(bufB, m2w2, m2b2, out,
                                                        NN, 100, 100, 4, 0);
}

// Round 10
// 1420.645 us; speedup vs baseline: 1.6588x; 1.0288x over previous
//
#include <hip/hip_runtime.h>

// RuleGraphNet: 2x TripleConv(+mlp), N=50000 nodes, E=800000 edges.
// eattr pre-converted to bf16[NE][128] once; MT GEMM is LDS-free (direct
// global bf16 A-fragments -> MFMA), both halves fused per conv. NT stored
// bf16. Aggregation: wave owns 2 dst nodes, lane owns column pair, register
// accumulation over BOTH phases in one dispatch; self fused; no LDS/atomics.

#define NN 50000
#define NE 800000
#define EHALF 400000
#define NN2 100000
#define GB 8            // edges batched per gather group

typedef __attribute__((ext_vector_type(4))) float  f32x4;
typedef __attribute__((ext_vector_type(8))) __bf16 bf16x8;
typedef __attribute__((ext_vector_type(4))) __bf16 bf16x4;

__device__ __forceinline__ float bf16lo(unsigned u) {
    union { unsigned u; float f; } c; c.u = u << 16; return c.f;
}
__device__ __forceinline__ float bf16hi(unsigned u) {
    union { unsigned u; float f; } c; c.u = u & 0xffff0000u; return c.f;
}

// ---------------- generic bf16 MFMA GEMM (LDS-staged A, fp32 in) ----------
// Out[M][ldo] = act(A[M][K] @ W[K][N] + bias). W k-rows guarded by Kw.
// OBF16: out bf16 (with bias, no relu), cols guarded by ldo.
template<int K, bool OBF16>
__global__ __launch_bounds__(256)
void mm_bf16(const float* __restrict__ A, const float* __restrict__ W,
             const float* __restrict__ bias, void* __restrict__ Outp,
             int Kw, int M, int N, int ldo, int RT, int relu)
{
    __shared__ __align__(16) __bf16 et[128 * 128];
    const int t = threadIdx.x;
    const int lane = t & 63, w = t >> 6;
    const int mh = w & 1, nh = w >> 1;
    const int l15 = lane & 15, l4 = lane >> 4;
    const int cb = blockIdx.y * 64;

    bf16x8 wf[2][4];
    const int colbase = cb + nh * 32 + l15;
    #pragma unroll
    for (int nt = 0; nt < 2; ++nt) {
        int col = colbase + nt * 16;
        #pragma unroll
        for (int ks = 0; ks < 4; ++ks) {
            bf16x8 f;
            #pragma unroll
            for (int j = 0; j < 8; ++j) {
                int k = ks * 32 + l4 * 8 + j;
                float v = (k < Kw && col < N) ? W[k * N + col] : 0.f;
                f[j] = (__bf16)v;
            }
            wf[nt][ks] = f;
        }
    }
    float bv[2] = {0.f, 0.f};
    if (bias) {
        #pragma unroll
        for (int nt = 0; nt < 2; ++nt) {
            int col = colbase + nt * 16;
            if (col < N) bv[nt] = bias[col];
        }
    }

    for (int it = 0; it < RT; ++it) {
        const int row0 = (blockIdx.x * RT + it) * 128;
        if (row0 >= M) break;
        __syncthreads();
        if constexpr (K % 4 == 0) {
            constexpr int QK = K / 4;
            for (int i = t; i < 128 * QK; i += 256) {
                int row = i / QK, q = i - row * QK;
                int gr = row0 + row;
                float4 v = {0.f, 0.f, 0.f, 0.f};
                if (gr < M) v = *(const float4*)(A + (size_t)gr * K + q * 4);
                bf16x4 b;
                b[0] = (__bf16)v.x; b[1] = (__bf16)v.y;
                b[2] = (__bf16)v.z; b[3] = (__bf16)v.w;
                *(bf16x4*)(et + row * 128 + ((q * 4) ^ ((row & 7) << 3))) = b;
            }
            constexpr int QP = (128 - K) / 4;
            if constexpr (QP > 0) {
                for (int i = t; i < 128 * QP; i += 256) {
                    int row = i / QP, q = QK + (i - (i / QP) * QP);
                    bf16x4 z;
                    z[0] = (__bf16)0.f; z[1] = (__bf16)0.f;
                    z[2] = (__bf16)0.f; z[3] = (__bf16)0.f;
                    *(bf16x4*)(et + row * 128 + ((q * 4) ^ ((row & 7) << 3))) = z;
                }
            }
        } else {
            for (int i = t; i < 128 * 128; i += 256) {
                int row = i >> 7, k = i & 127;
                int gr = row0 + row;
                float v = (k < K && gr < M) ? A[(size_t)gr * K + k] : 0.f;
                et[row * 128 + (k ^ ((row & 7) << 3))] = (__bf16)v;
            }
        }
        __syncthreads();

        f32x4 c[4][2] = {};
        #pragma unroll
        for (int ks = 0; ks < 4; ++ks) {
            #pragma unroll
            for (int mt = 0; mt < 4; ++mt) {
                int arow = mh * 64 + mt * 16 + l15;
                bf16x8 a = *(const bf16x8*)(et + arow * 128 +
                                            ((ks * 32 + l4 * 8) ^ ((l15 & 7) << 3)));
                c[mt][0] = __builtin_amdgcn_mfma_f32_16x16x32_bf16(a, wf[0][ks], c[mt][0], 0, 0, 0);
                c[mt][1] = __builtin_amdgcn_mfma_f32_16x16x32_bf16(a, wf[1][ks], c[mt][1], 0, 0, 0);
            }
        }

        #pragma unroll
        for (int mt = 0; mt < 4; ++mt) {
            #pragma unroll
            for (int nt = 0; nt < 2; ++nt) {
                int col = colbase + nt * 16;
                #pragma unroll
                for (int r = 0; r < 4; ++r) {
                    int row = row0 + mh * 64 + mt * 16 + l4 * 4 + r;
                    if constexpr (OBF16) {
                        if (row < M && col < ldo)
                            ((__bf16*)Outp)[(size_t)row * ldo + col] =
                                (__bf16)(c[mt][nt][r] + bv[nt]);
                    } else {
                        if (row < M && col < N) {
                            float v = c[mt][nt][r] + bv[nt];
                            if (relu) v = fmaxf(v, 0.f);
                            ((float*)Outp)[(size_t)row * ldo + col] = v;
                        }
                    }
                }
            }
        }
    }
}

// ---------------- eattr fp32 [NE][100] -> bf16 [NE][128] (zero-pad) -------
__global__ __launch_bounds__(256)
void cvt_eattr(const float* __restrict__ e, __bf16* __restrict__ ebf)
{
    int i = blockIdx.x * 256 + threadIdx.x;     // NE*16 threads, 8 cols each
    int row = i >> 4, oct = i & 15;
    if (row >= NE) return;
    bf16x8 o;
    if (oct < 12) {
        const float* p = e + (size_t)row * 100 + oct * 8;
        float4 v0 = *(const float4*)p;
        float4 v1 = *(const float4*)(p + 4);
        o[0] = (__bf16)v0.x; o[1] = (__bf16)v0.y; o[2] = (__bf16)v0.z; o[3] = (__bf16)v0.w;
        o[4] = (__bf16)v1.x; o[5] = (__bf16)v1.y; o[6] = (__bf16)v1.z; o[7] = (__bf16)v1.w;
    } else if (oct == 12) {
        float4 v0 = *(const float4*)(e + (size_t)row * 100 + 96);
        o[0] = (__bf16)v0.x; o[1] = (__bf16)v0.y; o[2] = (__bf16)v0.z; o[3] = (__bf16)v0.w;
        o[4] = (__bf16)0.f; o[5] = (__bf16)0.f; o[6] = (__bf16)0.f; o[7] = (__bf16)0.f;
    } else {
        #pragma unroll
        for (int j = 0; j < 8; ++j) o[j] = (__bf16)0.f;
    }
    *(bf16x8*)(ebf + (size_t)row * 128 + oct * 8) = o;
}

// ---------------- LDS-free MT GEMM: MT[e] = ebf[e] @ W  (both halves) -----
// grid (1250, 2), RT=5: blocks 0..624 -> half a (Wa), 625..1249 -> half b.
__global__ __launch_bounds__(256)
void mt_gemm(const __bf16* __restrict__ ebf,    // [NE][128]
             const float* __restrict__ Wa,      // [100][ND]
             const float* __restrict__ Wb,      // [100][ND]
             __bf16* __restrict__ MT,           // [NE][112]
             int ND, int RT)
{
    const int t = threadIdx.x;
    const int lane = t & 63, w = t >> 6;
    const int mh = w & 1, nh = w >> 1;
    const int l15 = lane & 15, l4 = lane >> 4;
    const float* W = (blockIdx.x < gridDim.x / 2) ? Wa : Wb;

    bf16x8 wf[2][4];
    const int colbase = blockIdx.y * 64 + nh * 32 + l15;
    #pragma unroll
    for (int nt = 0; nt < 2; ++nt) {
        int col = colbase + nt * 16;
        #pragma unroll
        for (int ks = 0; ks < 4; ++ks) {
            bf16x8 f;
            #pragma unroll
            for (int j = 0; j < 8; ++j) {
                int k = ks * 32 + l4 * 8 + j;
                float v = (k < 100 && col < ND) ? W[k * ND + col] : 0.f;
                f[j] = (__bf16)v;
            }
            wf[nt][ks] = f;
        }
    }

    for (int it = 0; it < RT; ++it) {
        const int row0 = (blockIdx.x * RT + it) * 128;
        f32x4 c[4][2] = {};
        #pragma unroll
        for (int ks = 0; ks < 4; ++ks) {
            #pragma unroll
            for (int mt = 0; mt < 4; ++mt) {
                int row = row0 + mh * 64 + mt * 16 + l15;
                bf16x8 a = *(const bf16x8*)(ebf + (size_t)row * 128 + ks * 32 + l4 * 8);
                c[mt][0] = __builtin_amdgcn_mfma_f32_16x16x32_bf16(a, wf[0][ks], c[mt][0], 0, 0, 0);
                c[mt][1] = __builtin_amdgcn_mfma_f32_16x16x32_bf16(a, wf[1][ks], c[mt][1], 0, 0, 0);
            }
        }
        #pragma unroll
        for (int mt = 0; mt < 4; ++mt) {
            #pragma unroll
            for (int nt = 0; nt < 2; ++nt) {
                int col = colbase + nt * 16;
                if (col < 112) {
                    #pragma unroll
                    for (int r = 0; r < 4; ++r) {
                        int row = row0 + mh * 64 + mt * 16 + l4 * 4 + r;
                        MT[(size_t)row * 112 + col] = (__bf16)c[mt][nt][r];
                    }
                }
            }
        }
    }
}

// ---------------- CSR build (edges sorted by dst, per half) ----------------
__global__ void zero_ints(int* __restrict__ p, int n)
{
    int i = blockIdx.x * 256 + threadIdx.x;
    if (i < n) p[i] = 0;
}

__global__ void count_edges(const int* __restrict__ dst, int* __restrict__ cnt)
{
    int e = blockIdx.x * 256 + threadIdx.x;
    if (e < NE) atomicAdd(&cnt[dst[e] + (e >= EHALF ? NN : 0)], 1);
}

__global__ void scan_blocks(const int* __restrict__ cnt, int* __restrict__ off,
                            int* __restrict__ bsum, int n)
{
    __shared__ int s[256];
    int t = threadIdx.x, g = blockIdx.x * 256 + t;
    int v = (g < n) ? cnt[g] : 0;
    s[t] = v; __syncthreads();
    for (int d = 1; d < 256; d <<= 1) {
        int add = (t >= d) ? s[t - d] : 0;
        __syncthreads();
        s[t] += add;
        __syncthreads();
    }
    if (g < n) off[g] = s[t] - v;
    if (t == 255) bsum[blockIdx.x] = s[255];
}

__global__ void scan_bsum(int* __restrict__ bsum, int nb)
{
    __shared__ int s[512];
    int t = threadIdx.x;
    int v = (t < nb) ? bsum[t] : 0;
    s[t] = v; __syncthreads();
    for (int d = 1; d < 512; d <<= 1) {
        int add = (t >= d) ? s[t - d] : 0;
        __syncthreads();
        s[t] += add;
        __syncthreads();
    }
    if (t < nb) bsum[t] = s[t] - v;
}

__global__ void scan_add(int* __restrict__ off, const int* __restrict__ bsum,
                         int* __restrict__ cur, int n)
{
    int g = blockIdx.x * 256 + threadIdx.x;
    if (g < n) { int o = off[g] + bsum[blockIdx.x]; off[g] = o; cur[g] = o; }
}

__global__ void scatter_edges(const int* __restrict__ eidx, int* __restrict__ cur,
                              int2* __restrict__ epk)
{
    int e = blockIdx.x * 256 + threadIdx.x;
    if (e < NE) {
        int s = eidx[e], d = eidx[NE + e];
        int pos = atomicAdd(&cur[d + (e >= EHALF ? NN : 0)], 1);
        int2 v; v.x = e; v.y = s;
        epk[pos] = v;
    }
}

// ---------------- edge_aggr2: both phases, register accumulation ----------
// Wave owns 2 dst nodes; lane owns column pair (2*lane, 2*lane+1). Per edge:
// one u32 MT load + one u32 NT[src] load (NT bf16). NT[dst] loaded once per
// node per phase. Output stride 112, pad cols zeroed (fast path for next GEMM).
template<int ND, int NTS>
__global__ __launch_bounds__(256)
void edge_aggr2(const __bf16* __restrict__ MT,    // [NE][112]
                const int2* __restrict__ epk,     // [NE] {edge, src} sorted
                const int* __restrict__ off,      // [NN2]
                const __bf16* __restrict__ NT,    // [NN][NTS] bf16
                const float* __restrict__ self,   // [NN][ND] fp32
                float* __restrict__ aggr,         // [NN][112]
                int blkd0, int blks0, int blkd1, int blks1)
{
    const int t = threadIdx.x;
    const int lane = t & 63, wv = t >> 6;
    const int c0 = lane * 2;
    const bool a0 = c0 < ND, a1 = c0 + 1 < ND;
    const int wid = blockIdx.x * 4 + wv;

    #pragma unroll
    for (int ni = 0; ni < 2; ++ni) {
        const int n = wid * 2 + ni;
        float acc0 = 0.f, acc1 = 0.f;

        #pragma unroll
        for (int phase = 0; phase < 2; ++phase) {
            const int blkd = phase ? blkd1 : blkd0;
            const int blks = phase ? blks1 : blks0;
            const int idx = phase * NN + n;
            const int pb = off[idx];
            const int pe = (idx + 1 == NN2) ? NE : off[idx + 1];

            float nd0 = 0.f, nd1 = 0.f;
            if (a0) {
                unsigned nd = *(const unsigned*)(NT + (size_t)n * NTS + blkd + c0);
                nd0 = bf16lo(nd); nd1 = bf16hi(nd);
            }

            for (int p = pb; p < pe; p += GB) {
                int ee[GB], ss[GB];
                #pragma unroll
                for (int i = 0; i < GB; ++i) {
                    int pp = p + i;
                    if (pp < pe) { int2 pk = epk[pp]; ee[i] = pk.x; ss[i] = pk.y; }
                    else         { ee[i] = -1; ss[i] = 0; }
                }
                unsigned mtw[GB], nsw[GB];
                #pragma unroll
                for (int i = 0; i < GB; ++i) {
                    mtw[i] = 0u; nsw[i] = 0u;
                    if (ee[i] >= 0 && a0) {
                        mtw[i] = *(const unsigned*)(MT + (size_t)ee[i] * 112 + c0);
                        nsw[i] = *(const unsigned*)(NT + (size_t)ss[i] * NTS + blks + c0);
                    }
                }
                #pragma unroll
                for (int i = 0; i < GB; ++i) {
                    if (ee[i] < 0) continue;          // wave-uniform
                    acc0 += fmaxf(bf16lo(mtw[i]) + nd0 + bf16lo(nsw[i]), 0.f);
                    acc1 += fmaxf(bf16hi(mtw[i]) + nd1 + bf16hi(nsw[i]), 0.f);
                }
            }
        }

        if (c0 < 112) {
            const size_t g0 = (size_t)n * 112 + c0;
            aggr[g0]     = a0 ? (acc0 + self[(size_t)n * ND + c0])     : 0.f;
            aggr[g0 + 1] = a1 ? (acc1 + self[(size_t)n * ND + c0 + 1]) : 0.f;
        }
    }
}

// ---------------- weight assembly (padded, 16B-aligned column blocks) -----
__global__ void assemble(const float* __restrict__ l1a, const float* __restrict__ l1ab,
                         const float* __restrict__ l1b, const float* __restrict__ l1bb,
                         const float* __restrict__ l2a, const float* __restrict__ l2ab,
                         const float* __restrict__ l2b, const float* __restrict__ l2bb,
                         float* __restrict__ W1, float* __restrict__ b1,
                         float* __restrict__ W2, float* __restrict__ b2)
{
    int i = blockIdx.x * 256 + threadIdx.x;
    if (i < 107 * 432) {
        int k = i / 432, c = i % 432;
        int q = c / 108, cc = c - q * 108;
        float v = 0.f;
        if (cc < 107) {
            if (q == 0)      v = l1a[k * 107 + cc];
            else if (q == 1) v = l1a[(207 + k) * 107 + cc];
            else if (q == 2) v = l1b[k * 107 + cc];
            else             v = l1b[(207 + k) * 107 + cc];
        }
        W1[i] = v;
    }
    if (i < 432) {
        int q = i / 108, cc = i - q * 108;
        b1[i] = (cc < 107) ? (q == 0 ? l1ab[cc] : (q == 3 ? l1bb[cc] : 0.f)) : 0.f;
    }
    if (i < 100 * 416) {
        int k = i / 416, c = i % 416;
        int q = c / 104, cc = c - q * 104;
        float v = 0.f;
        if (cc < 100) {
            if (q == 0)      v = l2a[k * 100 + cc];
            else if (q == 1) v = l2a[(200 + k) * 100 + cc];
            else if (q == 2) v = l2b[k * 100 + cc];
            else             v = l2b[(200 + k) * 100 + cc];
        }
        W2[i] = v;
    }
    if (i < 416) {
        int q = i / 104, cc = i - q * 104;
        b2[i] = (cc < 100) ? (q == 0 ? l2ab[cc] : (q == 3 ? l2bb[cc] : 0.f)) : 0.f;
    }
}

extern "C" void kernel_launch(void* const* d_in, const int* in_sizes, int n_in,
                              void* d_out, int out_size, void* d_ws, size_t ws_size,
                              hipStream_t stream)
{
    const float* x    = (const float*)d_in[0];
    const int*   eidx = (const int*)d_in[1];
    const float* eatt = (const float*)d_in[2];
    const float* l1aw = (const float*)d_in[3];
    const float* l1ab = (const float*)d_in[4];
    const float* l1bw = (const float*)d_in[5];
    const float* l1bb = (const float*)d_in[6];
    const float* m1w1 = (const float*)d_in[7];
    const float* m1b1 = (const float*)d_in[8];
    const float* m1w2 = (const float*)d_in[9];
    const float* m1b2 = (const float*)d_in[10];
    const float* l2aw = (const float*)d_in[11];
    const float* l2ab = (const float*)d_in[12];
    const float* l2bw = (const float*)d_in[13];
    const float* l2bb = (const float*)d_in[14];
    const float* m2w1 = (const float*)d_in[15];
    const float* m2b1 = (const float*)d_in[16];
    const float* m2w2 = (const float*)d_in[17];
    const float* m2b2 = (const float*)d_in[18];
    float* out = (float*)d_out;

    // workspace layout (4-byte units), ~520 MB
    float*  ws   = (float*)d_ws;
    __bf16* NTbf = (__bf16*)ws;                         // 50000*432 bf16 = 43.2 MB
    float*  bufA = ws + 10800000;                       // 50000*112 fp32
    float*  bufC = bufA + 5600000;                      // 50000*100 fp32 (h)
    float*  W1   = bufC + 5000000;                      // 46,224
    float*  b1v  = W1 + 46224;                          // 432
    float*  W2   = b1v + 432;                           // 41,600
    float*  b2v  = W2 + 41600;                          // 416
    int*    off  = (int*)(b2v + 416);                   // 100,000
    int*    cur  = off + NN2;                           // 100,000
    int*    bsum = cur + NN2;                           // 512
    int2*   epk  = (int2*)(bsum + 512);                 // 800,000 int2
    __bf16* ebf  = (__bf16*)(epk + NE);                 // 800,000*128 bf16 = 204.8 MB
    __bf16* MTb  = ebf + (size_t)NE * 128;              // 800,000*112 bf16 = 179.2 MB
    float*  bufB = (float*)MTb;                         // t1/t2 alias (disjoint lifetime)

    const int* dst = eidx + NE;

    assemble<<<181, 256, 0, stream>>>(l1aw, l1ab, l1bw, l1bb, l2aw, l2ab, l2bw, l2bb,
                                      W1, b1v, W2, b2v);

    // ---- eattr -> bf16[128] ----
    cvt_eattr<<<NE * 16 / 256, 256, 0, stream>>>(eatt, ebf);

    // ---- CSR build (dst-sorted, per half; emits packed epk) ----
    zero_ints<<<(NN2 + 255) / 256, 256, 0, stream>>>(cur, NN2);
    count_edges<<<(NE + 255) / 256, 256, 0, stream>>>(dst, cur);
    scan_blocks<<<(NN2 + 255) / 256, 256, 0, stream>>>(cur, off, bsum, NN2);
    scan_bsum<<<1, 512, 0, stream>>>(bsum, (NN2 + 255) / 256);
    scan_add<<<(NN2 + 255) / 256, 256, 0, stream>>>(off, bsum, cur, NN2);
    scatter_edges<<<(NE + 255) / 256, 256, 0, stream>>>(eidx, cur, epk);

    const int AG = NN / 8;   // 6250 blocks: 4 waves x 2 nodes each

    // ---- conv1 ----
    mm_bf16<107, true><<<dim3(98, 7), 256, 0, stream>>>(x, W1, b1v, NTbf,
                                                        107, NN, 432, 432, 4, 0);
    mt_gemm<<<dim3(1250, 2), 256, 0, stream>>>(ebf, l1aw + 107 * 107,
                                               l1bw + 107 * 107, MTb, 107, 5);
    edge_aggr2<107, 432><<<AG, 256, 0, stream>>>(MTb, epk, off, NTbf, x, bufA,
                                                 0, 108, 324, 216);
    mm_bf16<112, false><<<dim3(98, 2), 256, 0, stream>>>(bufA, m1w1, m1b1, bufB,
                                                         107, NN, 100, 100, 4, 1);
    mm_bf16<100, false><<<dim3(98, 2), 256, 0, stream>>>(bufB, m1w2, m1b2, bufC,
                                                         100, NN, 100, 100, 4, 1);

    // ---- conv2 ----  (h in bufC)
    mm_bf16<100, true><<<dim3(98, 7), 256, 0, stream>>>(bufC, W2, b2v, NTbf,
                                                        100, NN, 416, 416, 4, 0);
    mt_gemm<<<dim3(1250, 2), 256, 0, stream>>>(ebf, l2aw + 100 * 100,
                                               l2bw + 100 * 100, MTb, 100, 5);
    edge_aggr2<100, 416><<<AG, 256, 0, stream>>>(MTb, epk, off, NTbf, bufC, bufA,
                                                 0, 104, 312, 208);
    mm_bf16<112, false><<<dim3(98, 1), 256, 0, stream>>>(bufA, m2w1, m2b1, bufB,
                                                         100, NN, 64, 64, 4, 1);
    mm_bf16<64, false><<<dim3(98, 2), 256, 0, stream>>>(bufB, m2w2, m2b2, out,
                                                        64, NN, 100, 100, 4, 0);
}

// Round 11
// 1283.631 us; speedup vs baseline: 1.8359x; 1.1067x over previous
//
#include <hip/hip_runtime.h>

// RuleGraphNet: 2x TripleConv(+mlp), N=50000 nodes, E=800000 edges.
// eattr pre-converted to bf16[NE][128] once; MT GEMM is LDS-free on the input
// side (direct global bf16 A-fragments -> MFMA), full 128-col block so ebf is
// read once, C staged via LDS for full-line streaming writes. NT stored bf16.
// Aggregation: wave owns 2 dst nodes, lane owns column pair, register
// accumulation over BOTH phases in one dispatch; self fused; no LDS/atomics.

#define NN 50000
#define NE 800000
#define EHALF 400000
#define NN2 100000
#define GB 8            // edges batched per gather group

typedef __attribute__((ext_vector_type(4))) float  f32x4;
typedef __attribute__((ext_vector_type(8))) __bf16 bf16x8;
typedef __attribute__((ext_vector_type(4))) __bf16 bf16x4;

__device__ __forceinline__ float bf16lo(unsigned u) {
    union { unsigned u; float f; } c; c.u = u << 16; return c.f;
}
__device__ __forceinline__ float bf16hi(unsigned u) {
    union { unsigned u; float f; } c; c.u = u & 0xffff0000u; return c.f;
}

// ---------------- generic bf16 MFMA GEMM (LDS-staged A, fp32 in) ----------
// Out[M][ldo] = act(A[M][K] @ W[K][N] + bias). W k-rows guarded by Kw.
// OBF16: out bf16 (with bias, no relu), cols guarded by ldo.
template<int K, bool OBF16>
__global__ __launch_bounds__(256)
void mm_bf16(const float* __restrict__ A, const float* __restrict__ W,
             const float* __restrict__ bias, void* __restrict__ Outp,
             int Kw, int M, int N, int ldo, int RT, int relu)
{
    __shared__ __align__(16) __bf16 et[128 * 128];
    const int t = threadIdx.x;
    const int lane = t & 63, w = t >> 6;
    const int mh = w & 1, nh = w >> 1;
    const int l15 = lane & 15, l4 = lane >> 4;
    const int cb = blockIdx.y * 64;

    bf16x8 wf[2][4];
    const int colbase = cb + nh * 32 + l15;
    #pragma unroll
    for (int nt = 0; nt < 2; ++nt) {
        int col = colbase + nt * 16;
        #pragma unroll
        for (int ks = 0; ks < 4; ++ks) {
            bf16x8 f;
            #pragma unroll
            for (int j = 0; j < 8; ++j) {
                int k = ks * 32 + l4 * 8 + j;
                float v = (k < Kw && col < N) ? W[k * N + col] : 0.f;
                f[j] = (__bf16)v;
            }
            wf[nt][ks] = f;
        }
    }
    float bv[2] = {0.f, 0.f};
    if (bias) {
        #pragma unroll
        for (int nt = 0; nt < 2; ++nt) {
            int col = colbase + nt * 16;
            if (col < N) bv[nt] = bias[col];
        }
    }

    for (int it = 0; it < RT; ++it) {
        const int row0 = (blockIdx.x * RT + it) * 128;
        if (row0 >= M) break;
        __syncthreads();
        if constexpr (K % 4 == 0) {
            constexpr int QK = K / 4;
            for (int i = t; i < 128 * QK; i += 256) {
                int row = i / QK, q = i - row * QK;
                int gr = row0 + row;
                float4 v = {0.f, 0.f, 0.f, 0.f};
                if (gr < M) v = *(const float4*)(A + (size_t)gr * K + q * 4);
                bf16x4 b;
                b[0] = (__bf16)v.x; b[1] = (__bf16)v.y;
                b[2] = (__bf16)v.z; b[3] = (__bf16)v.w;
                *(bf16x4*)(et + row * 128 + ((q * 4) ^ ((row & 7) << 3))) = b;
            }
            constexpr int QP = (128 - K) / 4;
            if constexpr (QP > 0) {
                for (int i = t; i < 128 * QP; i += 256) {
                    int row = i / QP, q = QK + (i - (i / QP) * QP);
                    bf16x4 z;
                    z[0] = (__bf16)0.f; z[1] = (__bf16)0.f;
                    z[2] = (__bf16)0.f; z[3] = (__bf16)0.f;
                    *(bf16x4*)(et + row * 128 + ((q * 4) ^ ((row & 7) << 3))) = z;
                }
            }
        } else {
            for (int i = t; i < 128 * 128; i += 256) {
                int row = i >> 7, k = i & 127;
                int gr = row0 + row;
                float v = (k < K && gr < M) ? A[(size_t)gr * K + k] : 0.f;
                et[row * 128 + (k ^ ((row & 7) << 3))] = (__bf16)v;
            }
        }
        __syncthreads();

        f32x4 c[4][2] = {};
        #pragma unroll
        for (int ks = 0; ks < 4; ++ks) {
            #pragma unroll
            for (int mt = 0; mt < 4; ++mt) {
                int arow = mh * 64 + mt * 16 + l15;
                bf16x8 a = *(const bf16x8*)(et + arow * 128 +
                                            ((ks * 32 + l4 * 8) ^ ((l15 & 7) << 3)));
                c[mt][0] = __builtin_amdgcn_mfma_f32_16x16x32_bf16(a, wf[0][ks], c[mt][0], 0, 0, 0);
                c[mt][1] = __builtin_amdgcn_mfma_f32_16x16x32_bf16(a, wf[1][ks], c[mt][1], 0, 0, 0);
            }
        }

        #pragma unroll
        for (int mt = 0; mt < 4; ++mt) {
            #pragma unroll
            for (int nt = 0; nt < 2; ++nt) {
                int col = colbase + nt * 16;
                #pragma unroll
                for (int r = 0; r < 4; ++r) {
                    int row = row0 + mh * 64 + mt * 16 + l4 * 4 + r;
                    if constexpr (OBF16) {
                        if (row < M && col < ldo)
                            ((__bf16*)Outp)[(size_t)row * ldo + col] =
                                (__bf16)(c[mt][nt][r] + bv[nt]);
                    } else {
                        if (row < M && col < N) {
                            float v = c[mt][nt][r] + bv[nt];
                            if (relu) v = fmaxf(v, 0.f);
                            ((float*)Outp)[(size_t)row * ldo + col] = v;
                        }
                    }
                }
            }
        }
    }
}

// ---------------- eattr fp32 [NE][100] -> bf16 [NE][128] (zero-pad) -------
__global__ __launch_bounds__(256)
void cvt_eattr(const float* __restrict__ e, __bf16* __restrict__ ebf)
{
    int i = blockIdx.x * 256 + threadIdx.x;     // NE*16 threads, 8 cols each
    int row = i >> 4, oct = i & 15;
    if (row >= NE) return;
    bf16x8 o;
    if (oct < 12) {
        const float* p = e + (size_t)row * 100 + oct * 8;
        float4 v0 = *(const float4*)p;
        float4 v1 = *(const float4*)(p + 4);
        o[0] = (__bf16)v0.x; o[1] = (__bf16)v0.y; o[2] = (__bf16)v0.z; o[3] = (__bf16)v0.w;
        o[4] = (__bf16)v1.x; o[5] = (__bf16)v1.y; o[6] = (__bf16)v1.z; o[7] = (__bf16)v1.w;
    } else if (oct == 12) {
        float4 v0 = *(const float4*)(e + (size_t)row * 100 + 96);
        o[0] = (__bf16)v0.x; o[1] = (__bf16)v0.y; o[2] = (__bf16)v0.z; o[3] = (__bf16)v0.w;
        o[4] = (__bf16)0.f; o[5] = (__bf16)0.f; o[6] = (__bf16)0.f; o[7] = (__bf16)0.f;
    } else {
        #pragma unroll
        for (int j = 0; j < 8; ++j) o[j] = (__bf16)0.f;
    }
    *(bf16x8*)(ebf + (size_t)row * 128 + oct * 8) = o;
}

// ---------------- LDS-free-input MT GEMM (both halves, full 128 cols) -----
// grid (1250), RT=5: blocks 0..624 -> half a (Wa), 625..1249 -> half b.
// 4 waves: mh=rows half (64), nq=n-quad (64 cols). ebf read ONCE; C staged
// through LDS and written as contiguous bf16x8 (full-line streaming stores).
__global__ __launch_bounds__(256)
void mt_gemm(const __bf16* __restrict__ ebf,    // [NE][128]
             const float* __restrict__ Wa,      // [100][ND]
             const float* __restrict__ Wb,      // [100][ND]
             __bf16* __restrict__ MT,           // [NE][112]
             int ND, int RT)
{
    __shared__ __align__(16) __bf16 ct[128 * 112];   // 28 KB
    const int t = threadIdx.x;
    const int lane = t & 63, w = t >> 6;
    const int mh = w & 1, nq = w >> 1;
    const int l15 = lane & 15, l4 = lane >> 4;
    const float* W = (blockIdx.x < gridDim.x / 2) ? Wa : Wb;

    // W fragments: col = nq*64 + nt*16 + l15 (cols >= ND are zero)
    bf16x8 wf[4][4];
    const int colbase = nq * 64 + l15;
    #pragma unroll
    for (int nt = 0; nt < 4; ++nt) {
        int col = colbase + nt * 16;
        #pragma unroll
        for (int ks = 0; ks < 4; ++ks) {
            bf16x8 f;
            #pragma unroll
            for (int j = 0; j < 8; ++j) {
                int k = ks * 32 + l4 * 8 + j;
                float v = (k < 100 && col < ND) ? W[k * ND + col] : 0.f;
                f[j] = (__bf16)v;
            }
            wf[nt][ks] = f;
        }
    }

    for (int it = 0; it < RT; ++it) {
        const int row0 = (blockIdx.x * RT + it) * 128;
        f32x4 c[4][4] = {};
        #pragma unroll
        for (int ks = 0; ks < 4; ++ks) {
            #pragma unroll
            for (int mt = 0; mt < 4; ++mt) {
                int row = row0 + mh * 64 + mt * 16 + l15;
                bf16x8 a = *(const bf16x8*)(ebf + (size_t)row * 128 + ks * 32 + l4 * 8);
                #pragma unroll
                for (int nt = 0; nt < 4; ++nt)
                    c[mt][nt] = __builtin_amdgcn_mfma_f32_16x16x32_bf16(
                        a, wf[nt][ks], c[mt][nt], 0, 0, 0);
            }
        }
        __syncthreads();   // previous tile's copy-out has consumed ct
        #pragma unroll
        for (int mt = 0; mt < 4; ++mt) {
            #pragma unroll
            for (int nt = 0; nt < 4; ++nt) {
                int col = colbase + nt * 16;
                if (col < 112) {
                    #pragma unroll
                    for (int r = 0; r < 4; ++r) {
                        int lrow = mh * 64 + mt * 16 + l4 * 4 + r;
                        ct[lrow * 112 + col] = (__bf16)c[mt][nt][r];
                    }
                }
            }
        }
        __syncthreads();
        // contiguous copy-out: 128 rows x 112 cols x 2B = 28672 B = 1792 x 16B
        __bf16* gout = MT + (size_t)row0 * 112;
        for (int i = t; i < 1792; i += 256)
            *(bf16x8*)(gout + i * 8) = *(const bf16x8*)(ct + i * 8);
    }
}

// ---------------- CSR build (edges sorted by dst, per half) ----------------
__global__ void zero_ints(int* __restrict__ p, int n)
{
    int i = blockIdx.x * 256 + threadIdx.x;
    if (i < n) p[i] = 0;
}

__global__ void count_edges(const int* __restrict__ dst, int* __restrict__ cnt)
{
    int e = blockIdx.x * 256 + threadIdx.x;
    if (e < NE) atomicAdd(&cnt[dst[e] + (e >= EHALF ? NN : 0)], 1);
}

__global__ void scan_blocks(const int* __restrict__ cnt, int* __restrict__ off,
                            int* __restrict__ bsum, int n)
{
    __shared__ int s[256];
    int t = threadIdx.x, g = blockIdx.x * 256 + t;
    int v = (g < n) ? cnt[g] : 0;
    s[t] = v; __syncthreads();
    for (int d = 1; d < 256; d <<= 1) {
        int add = (t >= d) ? s[t - d] : 0;
        __syncthreads();
        s[t] += add;
        __syncthreads();
    }
    if (g < n) off[g] = s[t] - v;
    if (t == 255) bsum[blockIdx.x] = s[255];
}

__global__ void scan_bsum(int* __restrict__ bsum, int nb)
{
    __shared__ int s[512];
    int t = threadIdx.x;
    int v = (t < nb) ? bsum[t] : 0;
    s[t] = v; __syncthreads();
    for (int d = 1; d < 512; d <<= 1) {
        int add = (t >= d) ? s[t - d] : 0;
        __syncthreads();
        s[t] += add;
        __syncthreads();
    }
    if (t < nb) bsum[t] = s[t] - v;
}

__global__ void scan_add(int* __restrict__ off, const int* __restrict__ bsum,
                         int* __restrict__ cur, int n)
{
    int g = blockIdx.x * 256 + threadIdx.x;
    if (g < n) { int o = off[g] + bsum[blockIdx.x]; off[g] = o; cur[g] = o; }
}

__global__ void scatter_edges(const int* __restrict__ eidx, int* __restrict__ cur,
                              int2* __restrict__ epk)
{
    int e = blockIdx.x * 256 + threadIdx.x;
    if (e < NE) {
        int s = eidx[e], d = eidx[NE + e];
        int pos = atomicAdd(&cur[d + (e >= EHALF ? NN : 0)], 1);
        int2 v; v.x = e; v.y = s;
        epk[pos] = v;
    }
}

// ---------------- edge_aggr2: both phases, register accumulation ----------
// Wave owns 2 dst nodes; lane owns column pair (2*lane, 2*lane+1). Per edge:
// one u32 MT load + one u32 NT[src] load (NT bf16). NT[dst] loaded once per
// node per phase. Output stride 112, pad cols zeroed (fast path for next GEMM).
template<int ND, int NTS>
__global__ __launch_bounds__(256)
void edge_aggr2(const __bf16* __restrict__ MT,    // [NE][112]
                const int2* __restrict__ epk,     // [NE] {edge, src} sorted
                const int* __restrict__ off,      // [NN2]
                const __bf16* __restrict__ NT,    // [NN][NTS] bf16
                const float* __restrict__ self,   // [NN][ND] fp32
                float* __restrict__ aggr,         // [NN][112]
                int blkd0, int blks0, int blkd1, int blks1)
{
    const int t = threadIdx.x;
    const int lane = t & 63, wv = t >> 6;
    const int c0 = lane * 2;
    const bool a0 = c0 < ND, a1 = c0 + 1 < ND;
    const int wid = blockIdx.x * 4 + wv;

    #pragma unroll
    for (int ni = 0; ni < 2; ++ni) {
        const int n = wid * 2 + ni;
        float acc0 = 0.f, acc1 = 0.f;

        #pragma unroll
        for (int phase = 0; phase < 2; ++phase) {
            const int blkd = phase ? blkd1 : blkd0;
            const int blks = phase ? blks1 : blks0;
            const int idx = phase * NN + n;
            const int pb = off[idx];
            const int pe = (idx + 1 == NN2) ? NE : off[idx + 1];

            float nd0 = 0.f, nd1 = 0.f;
            if (a0) {
                unsigned nd = *(const unsigned*)(NT + (size_t)n * NTS + blkd + c0);
                nd0 = bf16lo(nd); nd1 = bf16hi(nd);
            }

            for (int p = pb; p < pe; p += GB) {
                int ee[GB], ss[GB];
                #pragma unroll
                for (int i = 0; i < GB; ++i) {
                    int pp = p + i;
                    if (pp < pe) { int2 pk = epk[pp]; ee[i] = pk.x; ss[i] = pk.y; }
                    else         { ee[i] = -1; ss[i] = 0; }
                }
                unsigned mtw[GB], nsw[GB];
                #pragma unroll
                for (int i = 0; i < GB; ++i) {
                    mtw[i] = 0u; nsw[i] = 0u;
                    if (ee[i] >= 0 && a0) {
                        mtw[i] = *(const unsigned*)(MT + (size_t)ee[i] * 112 + c0);
                        nsw[i] = *(const unsigned*)(NT + (size_t)ss[i] * NTS + blks + c0);
                    }
                }
                #pragma unroll
                for (int i = 0; i < GB; ++i) {
                    if (ee[i] < 0) continue;          // wave-uniform
                    acc0 += fmaxf(bf16lo(mtw[i]) + nd0 + bf16lo(nsw[i]), 0.f);
                    acc1 += fmaxf(bf16hi(mtw[i]) + nd1 + bf16hi(nsw[i]), 0.f);
                }
            }
        }

        if (c0 < 112) {
            const size_t g0 = (size_t)n * 112 + c0;
            aggr[g0]     = a0 ? (acc0 + self[(size_t)n * ND + c0])     : 0.f;
            aggr[g0 + 1] = a1 ? (acc1 + self[(size_t)n * ND + c0 + 1]) : 0.f;
        }
    }
}

// ---------------- weight assembly (padded, 16B-aligned column blocks) -----
__global__ void assemble(const float* __restrict__ l1a, const float* __restrict__ l1ab,
                         const float* __restrict__ l1b, const float* __restrict__ l1bb,
                         const float* __restrict__ l2a, const float* __restrict__ l2ab,
                         const float* __restrict__ l2b, const float* __restrict__ l2bb,
                         float* __restrict__ W1, float* __restrict__ b1,
                         float* __restrict__ W2, float* __restrict__ b2)
{
    int i = blockIdx.x * 256 + threadIdx.x;
    if (i < 107 * 432) {
        int k = i / 432, c = i % 432;
        int q = c / 108, cc = c - q * 108;
        float v = 0.f;
        if (cc < 107) {
            if (q == 0)      v = l1a[k * 107 + cc];
            else if (q == 1) v = l1a[(207 + k) * 107 + cc];
            else if (q == 2) v = l1b[k * 107 + cc];
            else             v = l1b[(207 + k) * 107 + cc];
        }
        W1[i] = v;
    }
    if (i < 432) {
        int q = i / 108, cc = i - q * 108;
        b1[i] = (cc < 107) ? (q == 0 ? l1ab[cc] : (q == 3 ? l1bb[cc] : 0.f)) : 0.f;
    }
    if (i < 100 * 416) {
        int k = i / 416, c = i % 416;
        int q = c / 104, cc = c - q * 104;
        float v = 0.f;
        if (cc < 100) {
            if (q == 0)      v = l2a[k * 100 + cc];
            else if (q == 1) v = l2a[(200 + k) * 100 + cc];
            else if (q == 2) v = l2b[k * 100 + cc];
            else             v = l2b[(200 + k) * 100 + cc];
        }
        W2[i] = v;
    }
    if (i < 416) {
        int q = i / 104, cc = i - q * 104;
        b2[i] = (cc < 100) ? (q == 0 ? l2ab[cc] : (q == 3 ? l2bb[cc] : 0.f)) : 0.f;
    }
}

extern "C" void kernel_launch(void* const* d_in, const int* in_sizes, int n_in,
                              void* d_out, int out_size, void* d_ws, size_t ws_size,
                              hipStream_t stream)
{
    const float* x    = (const float*)d_in[0];
    const int*   eidx = (const int*)d_in[1];
    const float* eatt = (const float*)d_in[2];
    const float* l1aw = (const float*)d_in[3];
    const float* l1ab = (const float*)d_in[4];
    const float* l1bw = (const float*)d_in[5];
    const float* l1bb = (const float*)d_in[6];
    const float* m1w1 = (const float*)d_in[7];
    const float* m1b1 = (const float*)d_in[8];
    const float* m1w2 = (const float*)d_in[9];
    const float* m1b2 = (const float*)d_in[10];
    const float* l2aw = (const float*)d_in[11];
    const float* l2ab = (const float*)d_in[12];
    const float* l2bw = (const float*)d_in[13];
    const float* l2bb = (const float*)d_in[14];
    const float* m2w1 = (const float*)d_in[15];
    const float* m2b1 = (const float*)d_in[16];
    const float* m2w2 = (const float*)d_in[17];
    const float* m2b2 = (const float*)d_in[18];
    float* out = (float*)d_out;

    // workspace layout (4-byte units), ~520 MB
    float*  ws   = (float*)d_ws;
    __bf16* NTbf = (__bf16*)ws;                         // 50000*432 bf16 = 43.2 MB
    float*  bufA = ws + 10800000;                       // 50000*112 fp32
    float*  bufC = bufA + 5600000;                      // 50000*100 fp32 (h)
    float*  W1   = bufC + 5000000;                      // 46,224
    float*  b1v  = W1 + 46224;                          // 432
    float*  W2   = b1v + 432;                           // 41,600
    float*  b2v  = W2 + 41600;                          // 416
    int*    off  = (int*)(b2v + 416);                   // 100,000
    int*    cur  = off + NN2;                           // 100,000
    int*    bsum = cur + NN2;                           // 512
    int2*   epk  = (int2*)(bsum + 512);                 // 800,000 int2
    __bf16* ebf  = (__bf16*)(epk + NE);                 // 800,000*128 bf16 = 204.8 MB
    __bf16* MTb  = ebf + (size_t)NE * 128;              // 800,000*112 bf16 = 179.2 MB
    float*  bufB = (float*)MTb;                         // t1/t2 alias (disjoint lifetime)

    const int* dst = eidx + NE;

    assemble<<<181, 256, 0, stream>>>(l1aw, l1ab, l1bw, l1bb, l2aw, l2ab, l2bw, l2bb,
                                      W1, b1v, W2, b2v);

    // ---- eattr -> bf16[128] ----
    cvt_eattr<<<NE * 16 / 256, 256, 0, stream>>>(eatt, ebf);

    // ---- CSR build (dst-sorted, per half; emits packed epk) ----
    zero_ints<<<(NN2 + 255) / 256, 256, 0, stream>>>(cur, NN2);
    count_edges<<<(NE + 255) / 256, 256, 0, stream>>>(dst, cur);
    scan_blocks<<<(NN2 + 255) / 256, 256, 0, stream>>>(cur, off, bsum, NN2);
    scan_bsum<<<1, 512, 0, stream>>>(bsum, (NN2 + 255) / 256);
    scan_add<<<(NN2 + 255) / 256, 256, 0, stream>>>(off, bsum, cur, NN2);
    scatter_edges<<<(NE + 255) / 256, 256, 0, stream>>>(eidx, cur, epk);

    const int AG = NN / 8;   // 6250 blocks: 4 waves x 2 nodes each

    // ---- conv1 ----
    mm_bf16<107, true><<<dim3(98, 7), 256, 0, stream>>>(x, W1, b1v, NTbf,
                                                        107, NN, 432, 432, 4, 0);
    mt_gemm<<<1250, 256, 0, stream>>>(ebf, l1aw + 107 * 107,
                                      l1bw + 107 * 107, MTb, 107, 5);
    edge_aggr2<107, 432><<<AG, 256, 0, stream>>>(MTb, epk, off, NTbf, x, bufA,
                                                 0, 108, 324, 216);
    mm_bf16<112, false><<<dim3(98, 2), 256, 0, stream>>>(bufA, m1w1, m1b1, bufB,
                                                         107, NN, 100, 100, 4, 1);
    mm_bf16<100, false><<<dim3(98, 2), 256, 0, stream>>>(bufB, m1w2, m1b2, bufC,
                                                         100, NN, 100, 100, 4, 1);

    // ---- conv2 ----  (h in bufC)
    mm_bf16<100, true><<<dim3(98, 7), 256, 0, stream>>>(bufC, W2, b2v, NTbf,
                                                        100, NN, 416, 416, 4, 0);
    mt_gemm<<<1250, 256, 0, stream>>>(ebf, l2aw + 100 * 100,
                                      l2bw + 100 * 100, MTb, 100, 5);
    edge_aggr2<100, 416><<<AG, 256, 0, stream>>>(MTb, epk, off, NTbf, bufC, bufA,
                                                 0, 104, 312, 208);
    mm_bf16<112, false><<<dim3(98, 1), 256, 0, stream>>>(bufA, m2w1, m2b1, bufB,
                                                         100, NN, 64, 64, 4, 1);
    mm_bf16<64, false><<<dim3(98, 2), 256, 0, stream>>>(bufB, m2w2, m2b2, out,
                                                        64, NN, 100, 100, 4, 0);
}